// Round 1
// baseline (321.645 us; speedup 1.0000x reference)
//
#include <hip/hip_runtime.h>
#include <math.h>

#define B_    8
#define T_    2000
#define H_    256
#define FOUT_ 257
#define ALEN_ 128
#define TQ    4

// ---------------------------------------------------------------------------
// act: 0 = none, 1 = tanh, 2 = sigmoid
template <int ACT>
__device__ __forceinline__ float apply_act(float x) {
    if constexpr (ACT == 1) return tanhf(x);
    else if constexpr (ACT == 2) return 1.f / (1.f + expf(-x));
    else return x;
}

// ---------------------------------------------------------------------------
// C[M,N] = act( A1 @ W[:, 0:K1]^T  (+ A2 @ W[:, K1:2*K1]^T)  + bias )
// A1, A2: [M, K1] row-major. W: [N, ldw] row-major. Tiled f32 GEMM.
// BM=128, BN=64, BK=32, 256 threads, 8x4 micro-tile per thread.
template <int ACT, bool HAS_A2>
__global__ __launch_bounds__(256) void gemm_awt(
    const float* __restrict__ A1, const float* __restrict__ A2,
    const float* __restrict__ W, const float* __restrict__ bias,
    float* __restrict__ C, int M, int N, int K1, int ldw)
{
    constexpr int BM = 128, BN = 64, BK = 32;
    __shared__ float As[BK][BM + 4];
    __shared__ float Ws[BK][BN + 4];

    const int tid = threadIdx.x;
    const int tx = tid & 15;        // 0..15 -> 4 output cols
    const int ty = tid >> 4;        // 0..15 -> 8 output rows
    const int m0 = blockIdx.x * BM;
    const int n0 = blockIdx.y * BN;
    const int lr = tid >> 3;        // 0..31 (tile row for loads)
    const int lc = (tid & 7) << 2;  // 0..28 (k offset for loads)

    float acc[8][4];
#pragma unroll
    for (int i = 0; i < 8; ++i)
#pragma unroll
        for (int j = 0; j < 4; ++j) acc[i][j] = 0.f;

    const int nkt = (HAS_A2 ? 2 : 1) * (K1 / BK);
    for (int kt = 0; kt < nkt; ++kt) {
        const int kglob = kt * BK;                    // column index into W
        const float* Asrc = (!HAS_A2 || kglob < K1) ? A1 : A2;
        const int k0l = HAS_A2 ? (kglob & (K1 - 1)) : kglob;  // K1=256 pow2

        __syncthreads();
        // A tile (128 x 32), stored transposed As[k][m]
#pragma unroll
        for (int r = 0; r < BM; r += 32) {
            const float4 v = *(const float4*)(Asrc + (size_t)(m0 + lr + r) * K1 + k0l + lc);
            As[lc + 0][lr + r] = v.x;
            As[lc + 1][lr + r] = v.y;
            As[lc + 2][lr + r] = v.z;
            As[lc + 3][lr + r] = v.w;
        }
        // W tile (64 x 32), stored transposed Ws[k][n]
#pragma unroll
        for (int r = 0; r < BN; r += 32) {
            const int n = n0 + lr + r;
            float4 v = make_float4(0.f, 0.f, 0.f, 0.f);
            if (n < N) v = *(const float4*)(W + (size_t)n * ldw + kglob + lc);
            Ws[lc + 0][lr + r] = v.x;
            Ws[lc + 1][lr + r] = v.y;
            Ws[lc + 2][lr + r] = v.z;
            Ws[lc + 3][lr + r] = v.w;
        }
        __syncthreads();

#pragma unroll
        for (int kk = 0; kk < BK; ++kk) {
            const float4 a0 = *(const float4*)&As[kk][ty * 8];
            const float4 a1 = *(const float4*)&As[kk][ty * 8 + 4];
            const float4 bv = *(const float4*)&Ws[kk][tx * 4];
            const float a[8] = {a0.x, a0.y, a0.z, a0.w, a1.x, a1.y, a1.z, a1.w};
            const float bb[4] = {bv.x, bv.y, bv.z, bv.w};
#pragma unroll
            for (int i = 0; i < 8; ++i)
#pragma unroll
                for (int j = 0; j < 4; ++j) acc[i][j] += a[i] * bb[j];
        }
    }

    const int row0 = m0 + ty * 8;
    const int col = n0 + (tx << 2);
    if (((N & 3) == 0) && (n0 + BN <= N)) {
        float4 bv = make_float4(0.f, 0.f, 0.f, 0.f);
        if (bias) bv = *(const float4*)&bias[col];
#pragma unroll
        for (int i = 0; i < 8; ++i) {
            float4 v;
            v.x = apply_act<ACT>(acc[i][0] + bv.x);
            v.y = apply_act<ACT>(acc[i][1] + bv.y);
            v.z = apply_act<ACT>(acc[i][2] + bv.z);
            v.w = apply_act<ACT>(acc[i][3] + bv.w);
            *(float4*)&C[(size_t)(row0 + i) * N + col] = v;
        }
    } else {
#pragma unroll
        for (int i = 0; i < 8; ++i)
#pragma unroll
            for (int j = 0; j < 4; ++j) {
                const int cc = col + j;
                if (cc < N) {
                    float x = acc[i][j] + (bias ? bias[cc] : 0.f);
                    C[(size_t)(row0 + i) * N + cc] = apply_act<ACT>(x);
                }
            }
    }
}

// ---------------------------------------------------------------------------
// Banded attention. Block = 256 threads handles TQ=4 consecutive t for one b.
// Band for row t: s in [max(0,t-ALEN), t]. Max is taken over the band only:
// the full-row max of the reference cancels exactly in the normalized weights
// (denominator >= 1 so the +1e-30 is ~1e-30 relative -> far below threshold).
__global__ __launch_bounds__(256) void band_attn(
    const float* __restrict__ qs, const float* __restrict__ kin,
    float* __restrict__ cout)
{
    __shared__ float wl[TQ][ALEN_ + TQ];  // scores -> weights, 4 x 132

    const int bid = blockIdx.x;
    const int b = bid / (T_ / TQ);
    const int t0 = (bid % (T_ / TQ)) * TQ;
    const int tid = threadIdx.x;
    const int lane = tid & 63;
    const int wv = tid >> 6;  // wave id 0..3

    const int s_lo = max(0, t0 - ALEN_);
    const int NS = (t0 + TQ - 1) - s_lo + 1;  // <= 132
    const size_t base = (size_t)b * T_ * H_;

    // each lane preloads its 4 qs values for the 4 query rows
    float4 qv[TQ];
#pragma unroll
    for (int tl = 0; tl < TQ; ++tl)
        qv[tl] = *(const float4*)(qs + base + (size_t)(t0 + tl) * H_ + lane * 4);

    // phase 1: scores. wave wv handles source rows j = wv, wv+4, ...
    for (int j = wv; j < NS; j += 4) {
        const float4 kv = *(const float4*)(kin + base + (size_t)(s_lo + j) * H_ + lane * 4);
        float p0 = kv.x * qv[0].x + kv.y * qv[0].y + kv.z * qv[0].z + kv.w * qv[0].w;
        float p1 = kv.x * qv[1].x + kv.y * qv[1].y + kv.z * qv[1].z + kv.w * qv[1].w;
        float p2 = kv.x * qv[2].x + kv.y * qv[2].y + kv.z * qv[2].z + kv.w * qv[2].w;
        float p3 = kv.x * qv[3].x + kv.y * qv[3].y + kv.z * qv[3].z + kv.w * qv[3].w;
#pragma unroll
        for (int off = 32; off; off >>= 1) {
            p0 += __shfl_xor(p0, off);
            p1 += __shfl_xor(p1, off);
            p2 += __shfl_xor(p2, off);
            p3 += __shfl_xor(p3, off);
        }
        if (lane == 0) {
            wl[0][j] = p0; wl[1][j] = p1; wl[2][j] = p2; wl[3][j] = p3;
        }
    }
    __syncthreads();

    // softmax (band max) — wave wv owns query row wv
    {
        const int tl = wv;
        const int t = t0 + tl;
        const int jlo = max(0, t - ALEN_) - s_lo;
        const int jhi = t - s_lo;
        float m = -INFINITY;
        for (int j = lane; j < NS; j += 64) {
            const float v = (j >= jlo && j <= jhi) ? wl[tl][j] : -INFINITY;
            m = fmaxf(m, v);
        }
#pragma unroll
        for (int off = 32; off; off >>= 1) m = fmaxf(m, __shfl_xor(m, off));
        float s = 0.f;
        for (int j = lane; j < NS; j += 64) {
            const float e = (j >= jlo && j <= jhi) ? expf(wl[tl][j] - m) : 0.f;
            wl[tl][j] = e;
            s += e;
        }
#pragma unroll
        for (int off = 32; off; off >>= 1) s += __shfl_xor(s, off);
        const float inv = 1.f / (s + 1e-30f);
        for (int j = lane; j < NS; j += 64) wl[tl][j] *= inv;
    }
    __syncthreads();

    // phase 2: c[t, h] = sum_j w[t][j] * k[s_lo+j, h]; thread = h
    float a0 = 0.f, a1 = 0.f, a2 = 0.f, a3 = 0.f;
    for (int j = 0; j < NS; ++j) {
        const float kv = kin[base + (size_t)(s_lo + j) * H_ + tid];
        a0 += wl[0][j] * kv;
        a1 += wl[1][j] * kv;
        a2 += wl[2][j] * kv;
        a3 += wl[3][j] * kv;
    }
    const size_t crow = ((size_t)b * T_ + t0) * H_ + tid;
    cout[crow + 0 * H_] = a0;
    cout[crow + 1 * H_] = a1;
    cout[crow + 2 * H_] = a2;
    cout[crow + 3 * H_] = a3;
}

// ---------------------------------------------------------------------------
extern "C" void kernel_launch(void* const* d_in, const int* in_sizes, int n_in,
                              void* d_out, int out_size, void* d_ws, size_t ws_size,
                              hipStream_t stream)
{
    const float* k       = (const float*)d_in[0];
    const float* q       = (const float*)d_in[1];
    const float* W_score = (const float*)d_in[2];
    const float* W_enh   = (const float*)d_in[3];
    const float* b_enh   = (const float*)d_in[4];
    const float* W_mask  = (const float*)d_in[5];
    const float* b_mask  = (const float*)d_in[6];
    float* out = (float*)d_out;

    float* ws = (float*)d_ws;
    float* qs = ws;                            // [16000, 256]
    float* c  = ws + (size_t)B_ * T_ * H_;     // [16000, 256]
    float* enh = qs;                           // reuse qs after attention

    const int M = B_ * T_;
    dim3 blk(256);

    // 1) qs = q @ W_score^T
    gemm_awt<0, false><<<dim3(M / 128, H_ / 64), blk, 0, stream>>>(
        q, nullptr, W_score, nullptr, qs, M, H_, H_, H_);

    // 2) banded attention -> c
    band_attn<<<dim3(B_ * T_ / TQ), blk, 0, stream>>>(qs, k, c);

    // 3) enh = tanh(c @ W_enh[:, :H]^T + q @ W_enh[:, H:]^T + b_enh)
    gemm_awt<1, true><<<dim3(M / 128, H_ / 64), blk, 0, stream>>>(
        c, q, W_enh, b_enh, enh, M, H_, H_, 2 * H_);

    // 4) out = sigmoid(enh @ W_mask^T + b_mask)
    gemm_awt<2, false><<<dim3(M / 128, (FOUT_ + 63) / 64), blk, 0, stream>>>(
        enh, nullptr, W_mask, b_mask, out, M, FOUT_, H_, H_);
}

// Round 2
// 251.149 us; speedup vs baseline: 1.2807x; 1.2807x over previous
//
#include <hip/hip_runtime.h>
#include <math.h>

#define B_    8
#define T_    2000
#define H_    256
#define FOUT_ 257
#define ALEN_ 128
#define TQ    4

// ---------------------------------------------------------------------------
// act: 0 = none, 1 = tanh, 2 = sigmoid
template <int ACT>
__device__ __forceinline__ float apply_act(float x) {
    if constexpr (ACT == 1) return tanhf(x);
    else if constexpr (ACT == 2) return 1.f / (1.f + expf(-x));
    else return x;
}

__device__ __forceinline__ float dot4(float4 a, float4 b) {
    return a.x * b.x + a.y * b.y + a.z * b.z + a.w * b.w;
}

// ---------------------------------------------------------------------------
// C[M,N] = act( A1 @ W[:, 0:K1]^T  (+ A2 @ W[:, K1:2*K1]^T)  + bias )
// A1, A2: [M, K1] row-major. W: [N, ldw] row-major. Tiled f32 GEMM.
template <int ACT, bool HAS_A2>
__global__ __launch_bounds__(256) void gemm_awt(
    const float* __restrict__ A1, const float* __restrict__ A2,
    const float* __restrict__ W, const float* __restrict__ bias,
    float* __restrict__ C, int M, int N, int K1, int ldw)
{
    constexpr int BM = 128, BN = 64, BK = 32;
    __shared__ float As[BK][BM + 4];
    __shared__ float Ws[BK][BN + 4];

    const int tid = threadIdx.x;
    const int tx = tid & 15;
    const int ty = tid >> 4;
    const int m0 = blockIdx.x * BM;
    const int n0 = blockIdx.y * BN;
    const int lr = tid >> 3;
    const int lc = (tid & 7) << 2;

    float acc[8][4];
#pragma unroll
    for (int i = 0; i < 8; ++i)
#pragma unroll
        for (int j = 0; j < 4; ++j) acc[i][j] = 0.f;

    const int nkt = (HAS_A2 ? 2 : 1) * (K1 / BK);
    for (int kt = 0; kt < nkt; ++kt) {
        const int kglob = kt * BK;
        const float* Asrc = (!HAS_A2 || kglob < K1) ? A1 : A2;
        const int k0l = HAS_A2 ? (kglob & (K1 - 1)) : kglob;

        __syncthreads();
#pragma unroll
        for (int r = 0; r < BM; r += 32) {
            const float4 v = *(const float4*)(Asrc + (size_t)(m0 + lr + r) * K1 + k0l + lc);
            As[lc + 0][lr + r] = v.x;
            As[lc + 1][lr + r] = v.y;
            As[lc + 2][lr + r] = v.z;
            As[lc + 3][lr + r] = v.w;
        }
#pragma unroll
        for (int r = 0; r < BN; r += 32) {
            const int n = n0 + lr + r;
            float4 v = make_float4(0.f, 0.f, 0.f, 0.f);
            if (n < N) v = *(const float4*)(W + (size_t)n * ldw + kglob + lc);
            Ws[lc + 0][lr + r] = v.x;
            Ws[lc + 1][lr + r] = v.y;
            Ws[lc + 2][lr + r] = v.z;
            Ws[lc + 3][lr + r] = v.w;
        }
        __syncthreads();

#pragma unroll
        for (int kk = 0; kk < BK; ++kk) {
            const float4 a0 = *(const float4*)&As[kk][ty * 8];
            const float4 a1 = *(const float4*)&As[kk][ty * 8 + 4];
            const float4 bv = *(const float4*)&Ws[kk][tx * 4];
            const float a[8] = {a0.x, a0.y, a0.z, a0.w, a1.x, a1.y, a1.z, a1.w};
            const float bb[4] = {bv.x, bv.y, bv.z, bv.w};
#pragma unroll
            for (int i = 0; i < 8; ++i)
#pragma unroll
                for (int j = 0; j < 4; ++j) acc[i][j] += a[i] * bb[j];
        }
    }

    const int row0 = m0 + ty * 8;
    const int col = n0 + (tx << 2);
    if (((N & 3) == 0) && (n0 + BN <= N)) {
        float4 bv = make_float4(0.f, 0.f, 0.f, 0.f);
        if (bias) bv = *(const float4*)&bias[col];
#pragma unroll
        for (int i = 0; i < 8; ++i) {
            float4 v;
            v.x = apply_act<ACT>(acc[i][0] + bv.x);
            v.y = apply_act<ACT>(acc[i][1] + bv.y);
            v.z = apply_act<ACT>(acc[i][2] + bv.z);
            v.w = apply_act<ACT>(acc[i][3] + bv.w);
            *(float4*)&C[(size_t)(row0 + i) * N + col] = v;
        }
    } else {
#pragma unroll
        for (int i = 0; i < 8; ++i)
#pragma unroll
            for (int j = 0; j < 4; ++j) {
                const int cc = col + j;
                if (cc < N) {
                    float x = acc[i][j] + (bias ? bias[cc] : 0.f);
                    C[(size_t)(row0 + i) * N + cc] = apply_act<ACT>(x);
                }
            }
    }
}

// ---------------------------------------------------------------------------
// Banded attention v2. Block = 256 threads (4 waves) handles TQ=4 consecutive
// t for one b. Band for row t: s in [max(0,t-ALEN), t]. Band-only max (exact
// substitution: full-row max cancels in normalized weights; denom >= 1 makes
// the +1e-30 a ~1e-30 relative term).
//
// Phase 1: 16-lane-group dot products. lane16 holds h-slice {l16*4 + c*64},
//   c=0..3, of all 4 query rows (qv regs). Each 16-lane group computes one
//   source row j; wave covers 4 rows/iter, block 16 rows/iter. Reduction is
//   4 shfl_xor steps (16-wide) instead of 6 (64-wide).
// Phase 2: wave wv owns query row wv; lane covers h = lane*4..+3 via float4
//   k loads (1 KB/wave per j, coalesced), unrolled x4 (NS % 4 == 0 always).
__global__ __launch_bounds__(256) void band_attn(
    const float* __restrict__ qs, const float* __restrict__ kin,
    float* __restrict__ cout)
{
    __shared__ float wl[TQ][ALEN_ + TQ];  // 4 x 132

    const int bid = blockIdx.x;
    const int b = bid / (T_ / TQ);
    const int t0 = (bid % (T_ / TQ)) * TQ;
    const int tid = threadIdx.x;
    const int lane = tid & 63;
    const int wv = tid >> 6;       // wave 0..3
    const int l16 = lane & 15;     // lane within 16-group
    const int grp = lane >> 4;     // group 0..3

    const int s_lo = max(0, t0 - ALEN_);
    const int NS = (t0 + TQ - 1) - s_lo + 1;  // <= 132, always multiple of 4
    const size_t base = (size_t)b * T_ * H_;

    // preload qs h-slices for the 4 query rows: h = l16*4 + c*64
    float4 qv[TQ][4];
#pragma unroll
    for (int tl = 0; tl < TQ; ++tl) {
        const float* qr = qs + base + (size_t)(t0 + tl) * H_ + l16 * 4;
#pragma unroll
        for (int c = 0; c < 4; ++c)
            qv[tl][c] = *(const float4*)(qr + c * 64);
    }

    // phase 1: scores
    for (int j0 = 0; j0 < NS; j0 += 16) {
        const int j = j0 + wv * 4 + grp;
        if (j < NS) {
            const float* kr = kin + base + (size_t)(s_lo + j) * H_ + l16 * 4;
            const float4 k0 = *(const float4*)(kr);
            const float4 k1 = *(const float4*)(kr + 64);
            const float4 k2 = *(const float4*)(kr + 128);
            const float4 k3 = *(const float4*)(kr + 192);
            float p[TQ];
#pragma unroll
            for (int tl = 0; tl < TQ; ++tl)
                p[tl] = dot4(k0, qv[tl][0]) + dot4(k1, qv[tl][1]) +
                        dot4(k2, qv[tl][2]) + dot4(k3, qv[tl][3]);
#pragma unroll
            for (int off = 1; off < 16; off <<= 1) {
#pragma unroll
                for (int tl = 0; tl < TQ; ++tl)
                    p[tl] += __shfl_xor(p[tl], off);
            }
            if (l16 == 0) {
#pragma unroll
                for (int tl = 0; tl < TQ; ++tl) wl[tl][j] = p[tl];
            }
        }
    }
    __syncthreads();

    // softmax over the band — wave wv owns query row wv
    {
        const int tl = wv;
        const int t = t0 + tl;
        const int jlo = max(0, t - ALEN_) - s_lo;
        const int jhi = t - s_lo;
        float m = -INFINITY;
        for (int j = lane; j < NS; j += 64) {
            const float v = (j >= jlo && j <= jhi) ? wl[tl][j] : -INFINITY;
            m = fmaxf(m, v);
        }
#pragma unroll
        for (int off = 32; off; off >>= 1) m = fmaxf(m, __shfl_xor(m, off));
        float s = 0.f;
        for (int j = lane; j < NS; j += 64) {
            const float e = (j >= jlo && j <= jhi) ? expf(wl[tl][j] - m) : 0.f;
            wl[tl][j] = e;
            s += e;
        }
#pragma unroll
        for (int off = 32; off; off >>= 1) s += __shfl_xor(s, off);
        const float inv = 1.f / (s + 1e-30f);
        for (int j = lane; j < NS; j += 64) wl[tl][j] *= inv;
    }
    __syncthreads();

    // phase 2: c[t0+wv, h] = sum_j w[j] * k[s_lo+j, h]; lane -> h = lane*4
    const float* kp = kin + base + (size_t)s_lo * H_ + lane * 4;
    float4 acc = make_float4(0.f, 0.f, 0.f, 0.f);
    for (int j = 0; j < NS; j += 4) {
        const float w0 = wl[wv][j + 0];
        const float w1 = wl[wv][j + 1];
        const float w2 = wl[wv][j + 2];
        const float w3 = wl[wv][j + 3];
        const float4 k0 = *(const float4*)(kp + (size_t)(j + 0) * H_);
        const float4 k1 = *(const float4*)(kp + (size_t)(j + 1) * H_);
        const float4 k2 = *(const float4*)(kp + (size_t)(j + 2) * H_);
        const float4 k3 = *(const float4*)(kp + (size_t)(j + 3) * H_);
        acc.x += w0 * k0.x + w1 * k1.x + w2 * k2.x + w3 * k3.x;
        acc.y += w0 * k0.y + w1 * k1.y + w2 * k2.y + w3 * k3.y;
        acc.z += w0 * k0.z + w1 * k1.z + w2 * k2.z + w3 * k3.z;
        acc.w += w0 * k0.w + w1 * k1.w + w2 * k2.w + w3 * k3.w;
    }
    *(float4*)&cout[((size_t)b * T_ + t0 + wv) * H_ + lane * 4] = acc;
}

// ---------------------------------------------------------------------------
extern "C" void kernel_launch(void* const* d_in, const int* in_sizes, int n_in,
                              void* d_out, int out_size, void* d_ws, size_t ws_size,
                              hipStream_t stream)
{
    const float* k       = (const float*)d_in[0];
    const float* q       = (const float*)d_in[1];
    const float* W_score = (const float*)d_in[2];
    const float* W_enh   = (const float*)d_in[3];
    const float* b_enh   = (const float*)d_in[4];
    const float* W_mask  = (const float*)d_in[5];
    const float* b_mask  = (const float*)d_in[6];
    float* out = (float*)d_out;

    float* ws = (float*)d_ws;
    float* qs = ws;                            // [16000, 256]
    float* c  = ws + (size_t)B_ * T_ * H_;     // [16000, 256]
    float* enh = qs;                           // reuse qs after attention

    const int M = B_ * T_;
    dim3 blk(256);

    // 1) qs = q @ W_score^T
    gemm_awt<0, false><<<dim3(M / 128, H_ / 64), blk, 0, stream>>>(
        q, nullptr, W_score, nullptr, qs, M, H_, H_, H_);

    // 2) banded attention -> c
    band_attn<<<dim3(B_ * T_ / TQ), blk, 0, stream>>>(qs, k, c);

    // 3) enh = tanh(c @ W_enh[:, :H]^T + q @ W_enh[:, H:]^T + b_enh)
    gemm_awt<1, true><<<dim3(M / 128, H_ / 64), blk, 0, stream>>>(
        c, q, W_enh, b_enh, enh, M, H_, H_, 2 * H_);

    // 4) out = sigmoid(enh @ W_mask^T + b_mask)
    gemm_awt<2, false><<<dim3(M / 128, (FOUT_ + 63) / 64), blk, 0, stream>>>(
        enh, nullptr, W_mask, b_mask, out, M, FOUT_, H_, H_);
}

// Round 3
// 232.602 us; speedup vs baseline: 1.3828x; 1.0797x over previous
//
#include <hip/hip_runtime.h>
#include <math.h>

#define B_    8
#define T_    2000
#define H_    256
#define FOUT_ 257
#define ALEN_ 128
#define TQ    4

// ---------------------------------------------------------------------------
// act: 0 = none, 1 = tanh, 2 = sigmoid
template <int ACT>
__device__ __forceinline__ float apply_act(float x) {
    if constexpr (ACT == 1) return tanhf(x);
    else if constexpr (ACT == 2) return 1.f / (1.f + expf(-x));
    else return x;
}

__device__ __forceinline__ float dot4(float4 a, float4 b) {
    return a.x * b.x + a.y * b.y + a.z * b.z + a.w * b.w;
}

// ---------------------------------------------------------------------------
// C[M,N] = act( A1 @ W[:, 0:K1]^T  (+ A2 @ W[:, K1:2*K1]^T)  + bias )
// A1, A2: [M, K1] row-major. W: [N, ldw] row-major. Tiled f32 GEMM.
template <int ACT, bool HAS_A2>
__global__ __launch_bounds__(256) void gemm_awt(
    const float* __restrict__ A1, const float* __restrict__ A2,
    const float* __restrict__ W, const float* __restrict__ bias,
    float* __restrict__ C, int M, int N, int K1, int ldw)
{
    constexpr int BM = 128, BN = 64, BK = 32;
    __shared__ float As[BK][BM + 4];
    __shared__ float Ws[BK][BN + 4];

    const int tid = threadIdx.x;
    const int tx = tid & 15;
    const int ty = tid >> 4;
    const int m0 = blockIdx.x * BM;
    const int n0 = blockIdx.y * BN;
    const int lr = tid >> 3;
    const int lc = (tid & 7) << 2;

    float acc[8][4];
#pragma unroll
    for (int i = 0; i < 8; ++i)
#pragma unroll
        for (int j = 0; j < 4; ++j) acc[i][j] = 0.f;

    const int nkt = (HAS_A2 ? 2 : 1) * (K1 / BK);
    for (int kt = 0; kt < nkt; ++kt) {
        const int kglob = kt * BK;
        const float* Asrc = (!HAS_A2 || kglob < K1) ? A1 : A2;
        const int k0l = HAS_A2 ? (kglob & (K1 - 1)) : kglob;

        __syncthreads();
#pragma unroll
        for (int r = 0; r < BM; r += 32) {
            const float4 v = *(const float4*)(Asrc + (size_t)(m0 + lr + r) * K1 + k0l + lc);
            As[lc + 0][lr + r] = v.x;
            As[lc + 1][lr + r] = v.y;
            As[lc + 2][lr + r] = v.z;
            As[lc + 3][lr + r] = v.w;
        }
#pragma unroll
        for (int r = 0; r < BN; r += 32) {
            const int n = n0 + lr + r;
            float4 v = make_float4(0.f, 0.f, 0.f, 0.f);
            if (n < N) v = *(const float4*)(W + (size_t)n * ldw + kglob + lc);
            Ws[lc + 0][lr + r] = v.x;
            Ws[lc + 1][lr + r] = v.y;
            Ws[lc + 2][lr + r] = v.z;
            Ws[lc + 3][lr + r] = v.w;
        }
        __syncthreads();

#pragma unroll
        for (int kk = 0; kk < BK; ++kk) {
            const float4 a0 = *(const float4*)&As[kk][ty * 8];
            const float4 a1 = *(const float4*)&As[kk][ty * 8 + 4];
            const float4 bv = *(const float4*)&Ws[kk][tx * 4];
            const float a[8] = {a0.x, a0.y, a0.z, a0.w, a1.x, a1.y, a1.z, a1.w};
            const float bb[4] = {bv.x, bv.y, bv.z, bv.w};
#pragma unroll
            for (int i = 0; i < 8; ++i)
#pragma unroll
                for (int j = 0; j < 4; ++j) acc[i][j] += a[i] * bb[j];
        }
    }

    const int row0 = m0 + ty * 8;
    const int col = n0 + (tx << 2);
    if (((N & 3) == 0) && (n0 + BN <= N)) {
        float4 bv = make_float4(0.f, 0.f, 0.f, 0.f);
        if (bias) bv = *(const float4*)&bias[col];
#pragma unroll
        for (int i = 0; i < 8; ++i) {
            float4 v;
            v.x = apply_act<ACT>(acc[i][0] + bv.x);
            v.y = apply_act<ACT>(acc[i][1] + bv.y);
            v.z = apply_act<ACT>(acc[i][2] + bv.z);
            v.w = apply_act<ACT>(acc[i][3] + bv.w);
            *(float4*)&C[(size_t)(row0 + i) * N + col] = v;
        }
    } else {
#pragma unroll
        for (int i = 0; i < 8; ++i)
#pragma unroll
            for (int j = 0; j < 4; ++j) {
                const int cc = col + j;
                if (cc < N) {
                    float x = acc[i][j] + (bias ? bias[cc] : 0.f);
                    C[(size_t)(row0 + i) * N + cc] = apply_act<ACT>(x);
                }
            }
    }
}

// ---------------------------------------------------------------------------
// Banded attention v3. Block = 256 threads (4 waves) handles TQ=4 consecutive
// t for one b. Band-only max (exact: full-row max cancels in the normalized
// weights; denom >= 1 makes the +1e-30 a ~1e-30 relative term).
//
// Phase 1: 16-lane-group dots; each group computes one source row j for all
//   4 query rows; block covers 16 j per iteration. k read once per block.
// Phase 2 (v3): j-tiled across waves — wave wv takes the j-chunk
//   [wv*NS/4, (wv+1)*NS/4) and accumulates partial c for ALL 4 query rows
//   (16 FMA per float4 k-load, 4x the arithmetic intensity of v2), then a
//   cross-wave LDS reduction combines the 4 partials. k read once per block
//   in phase 2 (vs 4x in v2): block k traffic 660 KB -> 264 KB.
__global__ __launch_bounds__(256) void band_attn(
    const float* __restrict__ qs, const float* __restrict__ kin,
    float* __restrict__ cout)
{
    __shared__ float wl[TQ][ALEN_ + TQ];   // 4 x 132 weights
    __shared__ float pr[4][TQ][H_];        // 16 KB partial c

    const int bid = blockIdx.x;
    const int b = bid / (T_ / TQ);
    const int t0 = (bid % (T_ / TQ)) * TQ;
    const int tid = threadIdx.x;
    const int lane = tid & 63;
    const int wv = tid >> 6;       // wave 0..3
    const int l16 = lane & 15;     // lane within 16-group
    const int grp = lane >> 4;     // group 0..3

    const int s_lo = max(0, t0 - ALEN_);
    const int NS = (t0 + TQ - 1) - s_lo + 1;  // <= 132, multiple of 4
    const size_t base = (size_t)b * T_ * H_;

    // preload qs h-slices for the 4 query rows: h = l16*4 + c*64
    float4 qv[TQ][4];
#pragma unroll
    for (int tl = 0; tl < TQ; ++tl) {
        const float* qr = qs + base + (size_t)(t0 + tl) * H_ + l16 * 4;
#pragma unroll
        for (int c = 0; c < 4; ++c)
            qv[tl][c] = *(const float4*)(qr + c * 64);
    }

    // phase 1: scores
    for (int j0 = 0; j0 < NS; j0 += 16) {
        const int j = j0 + wv * 4 + grp;
        if (j < NS) {
            const float* kr = kin + base + (size_t)(s_lo + j) * H_ + l16 * 4;
            const float4 k0 = *(const float4*)(kr);
            const float4 k1 = *(const float4*)(kr + 64);
            const float4 k2 = *(const float4*)(kr + 128);
            const float4 k3 = *(const float4*)(kr + 192);
            float p[TQ];
#pragma unroll
            for (int tl = 0; tl < TQ; ++tl)
                p[tl] = dot4(k0, qv[tl][0]) + dot4(k1, qv[tl][1]) +
                        dot4(k2, qv[tl][2]) + dot4(k3, qv[tl][3]);
#pragma unroll
            for (int off = 1; off < 16; off <<= 1) {
#pragma unroll
                for (int tl = 0; tl < TQ; ++tl)
                    p[tl] += __shfl_xor(p[tl], off);
            }
            if (l16 == 0) {
#pragma unroll
                for (int tl = 0; tl < TQ; ++tl) wl[tl][j] = p[tl];
            }
        }
    }
    __syncthreads();

    // softmax over the band — wave wv owns query row wv
    {
        const int tl = wv;
        const int t = t0 + tl;
        const int jlo = max(0, t - ALEN_) - s_lo;
        const int jhi = t - s_lo;
        float m = -INFINITY;
        for (int j = lane; j < NS; j += 64) {
            const float v = (j >= jlo && j <= jhi) ? wl[tl][j] : -INFINITY;
            m = fmaxf(m, v);
        }
#pragma unroll
        for (int off = 32; off; off >>= 1) m = fmaxf(m, __shfl_xor(m, off));
        float s = 0.f;
        for (int j = lane; j < NS; j += 64) {
            const float e = (j >= jlo && j <= jhi) ? expf(wl[tl][j] - m) : 0.f;
            wl[tl][j] = e;
            s += e;
        }
#pragma unroll
        for (int off = 32; off; off >>= 1) s += __shfl_xor(s, off);
        const float inv = 1.f / (s + 1e-30f);
        for (int j = lane; j < NS; j += 64) wl[tl][j] *= inv;
    }
    __syncthreads();

    // phase 2: wave wv handles j in [wv*chunk, (wv+1)*chunk) for ALL 4 rows
    const int chunk = NS >> 2;
    const int jbeg = wv * chunk;
    const int jend = jbeg + chunk;
    float4 acc[TQ];
#pragma unroll
    for (int tl = 0; tl < TQ; ++tl) acc[tl] = make_float4(0.f, 0.f, 0.f, 0.f);

    const float* kp = kin + base + (size_t)s_lo * H_ + lane * 4;
    for (int j = jbeg; j < jend; ++j) {
        const float4 kv = *(const float4*)(kp + (size_t)j * H_);
#pragma unroll
        for (int tl = 0; tl < TQ; ++tl) {
            const float w = wl[tl][j];
            acc[tl].x += w * kv.x;
            acc[tl].y += w * kv.y;
            acc[tl].z += w * kv.z;
            acc[tl].w += w * kv.w;
        }
    }
#pragma unroll
    for (int tl = 0; tl < TQ; ++tl)
        *(float4*)&pr[wv][tl][lane * 4] = acc[tl];
    __syncthreads();

    // cross-wave reduce: wave wv sums the 4 partials of query row wv
    float4 s0 = *(const float4*)&pr[0][wv][lane * 4];
    const float4 s1 = *(const float4*)&pr[1][wv][lane * 4];
    const float4 s2 = *(const float4*)&pr[2][wv][lane * 4];
    const float4 s3 = *(const float4*)&pr[3][wv][lane * 4];
    s0.x += s1.x + s2.x + s3.x;
    s0.y += s1.y + s2.y + s3.y;
    s0.z += s1.z + s2.z + s3.z;
    s0.w += s1.w + s2.w + s3.w;
    *(float4*)&cout[((size_t)b * T_ + t0 + wv) * H_ + lane * 4] = s0;
}

// ---------------------------------------------------------------------------
extern "C" void kernel_launch(void* const* d_in, const int* in_sizes, int n_in,
                              void* d_out, int out_size, void* d_ws, size_t ws_size,
                              hipStream_t stream)
{
    const float* k       = (const float*)d_in[0];
    const float* q       = (const float*)d_in[1];
    const float* W_score = (const float*)d_in[2];
    const float* W_enh   = (const float*)d_in[3];
    const float* b_enh   = (const float*)d_in[4];
    const float* W_mask  = (const float*)d_in[5];
    const float* b_mask  = (const float*)d_in[6];
    float* out = (float*)d_out;

    float* ws = (float*)d_ws;
    float* qs = ws;                            // [16000, 256]
    float* c  = ws + (size_t)B_ * T_ * H_;     // [16000, 256]
    float* enh = qs;                           // reuse qs after attention

    const int M = B_ * T_;
    dim3 blk(256);

    // 1) qs = q @ W_score^T
    gemm_awt<0, false><<<dim3(M / 128, H_ / 64), blk, 0, stream>>>(
        q, nullptr, W_score, nullptr, qs, M, H_, H_, H_);

    // 2) banded attention -> c
    band_attn<<<dim3(B_ * T_ / TQ), blk, 0, stream>>>(qs, k, c);

    // 3) enh = tanh(c @ W_enh[:, :H]^T + q @ W_enh[:, H:]^T + b_enh)
    gemm_awt<1, true><<<dim3(M / 128, H_ / 64), blk, 0, stream>>>(
        c, q, W_enh, b_enh, enh, M, H_, H_, 2 * H_);

    // 4) out = sigmoid(enh @ W_mask^T + b_mask)
    gemm_awt<2, false><<<dim3(M / 128, (FOUT_ + 63) / 64), blk, 0, stream>>>(
        enh, nullptr, W_mask, b_mask, out, M, FOUT_, H_, H_);
}

// Round 4
// 172.259 us; speedup vs baseline: 1.8672x; 1.3503x over previous
//
#include <hip/hip_runtime.h>
#include <math.h>

#define B_    8
#define T_    2000
#define H_    256
#define FOUT_ 257
#define ALEN_ 128
#define TQ    4

typedef __attribute__((ext_vector_type(8))) short bf16x8;
typedef __attribute__((ext_vector_type(16))) float f32x16;

// ---------------------------------------------------------------------------
__device__ __forceinline__ unsigned short f2bf(float x) {
    unsigned u = __builtin_bit_cast(unsigned, x);
    return (unsigned short)((u + 0x7FFFu + ((u >> 16) & 1u)) >> 16);
}
__device__ __forceinline__ float bf2f(unsigned short h) {
    unsigned u = ((unsigned)h) << 16;
    return __builtin_bit_cast(float, u);
}
__device__ __forceinline__ void gld16(const void* g, void* l) {
    __builtin_amdgcn_global_load_lds(
        (const __attribute__((address_space(1))) unsigned*)g,
        (__attribute__((address_space(3))) unsigned*)l, 16, 0, 0);
}
__device__ __forceinline__ float dot4(float4 a, float4 b) {
    return a.x * b.x + a.y * b.y + a.z * b.z + a.w * b.w;
}

// ---------------------------------------------------------------------------
// Split f32 weights into bf16 hi/lo. Segments: blocks [0,256) W_score (256x256),
// [256,768) W_enh (256x512), [768,1088) W_mask padded to 320x256 (zero rows>=257).
__global__ __launch_bounds__(256) void split_weights(
    const float* __restrict__ Ws, const float* __restrict__ We,
    const float* __restrict__ Wm,
    unsigned short* __restrict__ wsh, unsigned short* __restrict__ wsl,
    unsigned short* __restrict__ weh, unsigned short* __restrict__ wel,
    unsigned short* __restrict__ wmh, unsigned short* __restrict__ wml)
{
    const int bx = blockIdx.x, tid = threadIdx.x;
    if (bx < 256) {
        const int idx = bx * 256 + tid;
        const float x = Ws[idx];
        const unsigned short h = f2bf(x);
        wsh[idx] = h; wsl[idx] = f2bf(x - bf2f(h));
    } else if (bx < 768) {
        const int idx = (bx - 256) * 256 + tid;
        const float x = We[idx];
        const unsigned short h = f2bf(x);
        weh[idx] = h; wel[idx] = f2bf(x - bf2f(h));
    } else {
        const int idx = (bx - 768) * 256 + tid;  // 320*256 = 81920
        const int r = idx >> 8;                  // /256 cols
        const float x = (r < FOUT_) ? Wm[idx] : 0.f;
        const unsigned short h = f2bf(x);
        wmh[idx] = h; wml[idx] = f2bf(x - bf2f(h));
    }
}

// ---------------------------------------------------------------------------
// Split-bf16 MFMA GEMM:  C[M,N] = act( A @ W^T + bias ),  A f32 [M,256] (or
// concat of A1,A2 along K when HAS_A2), W pre-split bf16 hi/lo [Npad, KB].
// 3-term product: Ahi*Whi + Ahi*Wlo + Alo*Whi (err ~2^-16 rel).
// Block 256 thr (4 waves), tile 128x64, BK=32, wave tile 64x32 via
// mfma_f32_32x32x16_bf16. Double-buffered LDS, 2-phase pipeline (stage next
// before compute; single vmcnt-drain+barrier per K-tile). A staged via
// reg->split->ds_write; W via global_load_lds (pre-swizzled source, rule #21).
// LDS XOR swizzle: byte ^= (row&3)<<4 within each 64B row (both sides).
template <int ACT, bool HAS_A2>
__global__ __launch_bounds__(256) void gemm_mfma(
    const float* __restrict__ A1, const float* __restrict__ A2,
    const unsigned short* __restrict__ Wh, const unsigned short* __restrict__ Wl,
    const float* __restrict__ bias, float* __restrict__ C,
    int NT, int KB, int NSTORE, int LDC)
{
    __shared__ unsigned short AH[2][128 * 32];
    __shared__ unsigned short AL[2][128 * 32];
    __shared__ unsigned short BH[2][64 * 32];
    __shared__ unsigned short BL[2][64 * 32];

    const int tid = threadIdx.x;
    const int m0 = blockIdx.x * 128;
    const int n0 = blockIdx.y * 64;
    const int w = tid >> 6, l = tid & 63;
    const int wr = w >> 1, wc = w & 1;   // wave tile: rows wr*64..+63, cols wc*32..+31
    const int lm = l & 31, hh = l >> 5;

    f32x16 acc0 = {};
    f32x16 acc1 = {};
    float4 areg[4];

    auto LOADA = [&](int kt) {
        const int k0 = kt * 32;
        const float* base = A1;
        int kk = k0;
        if (HAS_A2 && k0 >= 256) { base = A2; kk = k0 - 256; }
#pragma unroll
        for (int p = 0; p < 4; ++p) {
            const int row = p * 32 + (tid >> 3);
            areg[p] = *(const float4*)(base + (size_t)(m0 + row) * 256 + kk + (tid & 7) * 4);
        }
    };
    auto WRITEA = [&](int buf) {
#pragma unroll
        for (int p = 0; p < 4; ++p) {
            const int row = p * 32 + (tid >> 3);
            const unsigned off = row * 64 + ((((tid & 7) * 8)) ^ ((row & 3) << 4));
            const float x0 = areg[p].x, x1 = areg[p].y, x2 = areg[p].z, x3 = areg[p].w;
            const unsigned short h0 = f2bf(x0), h1 = f2bf(x1), h2 = f2bf(x2), h3 = f2bf(x3);
            short4 hv = make_short4((short)h0, (short)h1, (short)h2, (short)h3);
            short4 lv = make_short4((short)f2bf(x0 - bf2f(h0)), (short)f2bf(x1 - bf2f(h1)),
                                    (short)f2bf(x2 - bf2f(h2)), (short)f2bf(x3 - bf2f(h3)));
            *(short4*)((char*)AH[buf] + off) = hv;
            *(short4*)((char*)AL[buf] + off) = lv;
        }
    };
    auto STAGEW = [&](int kt, int buf) {
        const int k0 = kt * 32;
        const int row = tid >> 2, slot = tid & 3;
        const size_t so = (size_t)(n0 + row) * KB + k0 + (size_t)((slot ^ (row & 3)) * 8);
        char* dh = (char*)BH[buf] + (tid >> 6) * 1024;
        char* dl = (char*)BL[buf] + (tid >> 6) * 1024;
        gld16(Wh + so, dh);
        gld16(Wl + so, dl);
    };

    // prologue: stage tile 0
    LOADA(0);
    STAGEW(0, 0);
    WRITEA(0);
    __syncthreads();

    int buf = 0;
    for (int kt = 0; kt < NT; ++kt) {
        const bool last = (kt == NT - 1);
        if (!last) { LOADA(kt + 1); STAGEW(kt + 1, buf ^ 1); }

#pragma unroll
        for (int kc = 0; kc < 2; ++kc) {
            const unsigned kslot = (unsigned)((kc * 2 + hh) * 16);
            const unsigned bo = (unsigned)((wc * 32 + lm) * 64) + (kslot ^ ((lm & 3) << 4));
            const bf16x8 bh = *(const bf16x8*)((const char*)BH[buf] + bo);
            const bf16x8 bl = *(const bf16x8*)((const char*)BL[buf] + bo);
            const unsigned r0 = (unsigned)(wr * 64 + lm);
            const unsigned ao0 = r0 * 64 + (kslot ^ ((r0 & 3) << 4));
            const unsigned ao1 = ao0 + 32 * 64;
            const bf16x8 ah0 = *(const bf16x8*)((const char*)AH[buf] + ao0);
            const bf16x8 al0 = *(const bf16x8*)((const char*)AL[buf] + ao0);
            const bf16x8 ah1 = *(const bf16x8*)((const char*)AH[buf] + ao1);
            const bf16x8 al1 = *(const bf16x8*)((const char*)AL[buf] + ao1);
            acc0 = __builtin_amdgcn_mfma_f32_32x32x16_bf16(ah0, bh, acc0, 0, 0, 0);
            acc0 = __builtin_amdgcn_mfma_f32_32x32x16_bf16(ah0, bl, acc0, 0, 0, 0);
            acc0 = __builtin_amdgcn_mfma_f32_32x32x16_bf16(al0, bh, acc0, 0, 0, 0);
            acc1 = __builtin_amdgcn_mfma_f32_32x32x16_bf16(ah1, bh, acc1, 0, 0, 0);
            acc1 = __builtin_amdgcn_mfma_f32_32x32x16_bf16(ah1, bl, acc1, 0, 0, 0);
            acc1 = __builtin_amdgcn_mfma_f32_32x32x16_bf16(al1, bh, acc1, 0, 0, 0);
        }

        if (!last) WRITEA(buf ^ 1);
        __syncthreads();
        buf ^= 1;
    }

    // epilogue: C/D layout col=lane&31, row=(reg&3)+8*(reg>>2)+4*(lane>>5)
    const int gcol = n0 + wc * 32 + lm;
    if (gcol < NSTORE) {
        const float bv = bias ? bias[gcol] : 0.f;
#pragma unroll
        for (int rt = 0; rt < 2; ++rt) {
            const f32x16 r = rt ? acc1 : acc0;
#pragma unroll
            for (int e = 0; e < 16; ++e) {
                const int rowl = (e & 3) + 8 * (e >> 2) + 4 * hh;
                const int gr = m0 + wr * 64 + rt * 32 + rowl;
                float x = r[e] + bv;
                if constexpr (ACT == 1) x = tanhf(x);
                else if constexpr (ACT == 2) x = 1.f / (1.f + expf(-x));
                C[(size_t)gr * LDC + gcol] = x;
            }
        }
    }
}

// ---------------------------------------------------------------------------
// Banded attention (unchanged from R3). Band-only max is exact (full-row max
// cancels in normalized weights; denom>=1 makes +1e-30 a ~1e-30 rel term).
__global__ __launch_bounds__(256) void band_attn(
    const float* __restrict__ qs, const float* __restrict__ kin,
    float* __restrict__ cout)
{
    __shared__ float wl[TQ][ALEN_ + TQ];
    __shared__ float pr[4][TQ][H_];

    const int bid = blockIdx.x;
    const int b = bid / (T_ / TQ);
    const int t0 = (bid % (T_ / TQ)) * TQ;
    const int tid = threadIdx.x;
    const int lane = tid & 63;
    const int wv = tid >> 6;
    const int l16 = lane & 15;
    const int grp = lane >> 4;

    const int s_lo = max(0, t0 - ALEN_);
    const int NS = (t0 + TQ - 1) - s_lo + 1;
    const size_t base = (size_t)b * T_ * H_;

    float4 qv[TQ][4];
#pragma unroll
    for (int tl = 0; tl < TQ; ++tl) {
        const float* qr = qs + base + (size_t)(t0 + tl) * H_ + l16 * 4;
#pragma unroll
        for (int c = 0; c < 4; ++c)
            qv[tl][c] = *(const float4*)(qr + c * 64);
    }

    for (int j0 = 0; j0 < NS; j0 += 16) {
        const int j = j0 + wv * 4 + grp;
        if (j < NS) {
            const float* kr = kin + base + (size_t)(s_lo + j) * H_ + l16 * 4;
            const float4 k0 = *(const float4*)(kr);
            const float4 k1 = *(const float4*)(kr + 64);
            const float4 k2 = *(const float4*)(kr + 128);
            const float4 k3 = *(const float4*)(kr + 192);
            float p[TQ];
#pragma unroll
            for (int tl = 0; tl < TQ; ++tl)
                p[tl] = dot4(k0, qv[tl][0]) + dot4(k1, qv[tl][1]) +
                        dot4(k2, qv[tl][2]) + dot4(k3, qv[tl][3]);
#pragma unroll
            for (int off = 1; off < 16; off <<= 1) {
#pragma unroll
                for (int tl = 0; tl < TQ; ++tl)
                    p[tl] += __shfl_xor(p[tl], off);
            }
            if (l16 == 0) {
#pragma unroll
                for (int tl = 0; tl < TQ; ++tl) wl[tl][j] = p[tl];
            }
        }
    }
    __syncthreads();

    {
        const int tl = wv;
        const int t = t0 + tl;
        const int jlo = max(0, t - ALEN_) - s_lo;
        const int jhi = t - s_lo;
        float m = -INFINITY;
        for (int j = lane; j < NS; j += 64) {
            const float v = (j >= jlo && j <= jhi) ? wl[tl][j] : -INFINITY;
            m = fmaxf(m, v);
        }
#pragma unroll
        for (int off = 32; off; off >>= 1) m = fmaxf(m, __shfl_xor(m, off));
        float s = 0.f;
        for (int j = lane; j < NS; j += 64) {
            const float e = (j >= jlo && j <= jhi) ? expf(wl[tl][j] - m) : 0.f;
            wl[tl][j] = e;
            s += e;
        }
#pragma unroll
        for (int off = 32; off; off >>= 1) s += __shfl_xor(s, off);
        const float inv = 1.f / (s + 1e-30f);
        for (int j = lane; j < NS; j += 64) wl[tl][j] *= inv;
    }
    __syncthreads();

    const int chunk = NS >> 2;
    const int jbeg = wv * chunk;
    const int jend = jbeg + chunk;
    float4 acc[TQ];
#pragma unroll
    for (int tl = 0; tl < TQ; ++tl) acc[tl] = make_float4(0.f, 0.f, 0.f, 0.f);

    const float* kp = kin + base + (size_t)s_lo * H_ + lane * 4;
    for (int j = jbeg; j < jend; ++j) {
        const float4 kv = *(const float4*)(kp + (size_t)j * H_);
#pragma unroll
        for (int tl = 0; tl < TQ; ++tl) {
            const float ww = wl[tl][j];
            acc[tl].x += ww * kv.x;
            acc[tl].y += ww * kv.y;
            acc[tl].z += ww * kv.z;
            acc[tl].w += ww * kv.w;
        }
    }
#pragma unroll
    for (int tl = 0; tl < TQ; ++tl)
        *(float4*)&pr[wv][tl][lane * 4] = acc[tl];
    __syncthreads();

    float4 s0 = *(const float4*)&pr[0][wv][lane * 4];
    const float4 s1 = *(const float4*)&pr[1][wv][lane * 4];
    const float4 s2 = *(const float4*)&pr[2][wv][lane * 4];
    const float4 s3 = *(const float4*)&pr[3][wv][lane * 4];
    s0.x += s1.x + s2.x + s3.x;
    s0.y += s1.y + s2.y + s3.y;
    s0.z += s1.z + s2.z + s3.z;
    s0.w += s1.w + s2.w + s3.w;
    *(float4*)&cout[((size_t)b * T_ + t0 + wv) * H_ + lane * 4] = s0;
}

// ---------------------------------------------------------------------------
extern "C" void kernel_launch(void* const* d_in, const int* in_sizes, int n_in,
                              void* d_out, int out_size, void* d_ws, size_t ws_size,
                              hipStream_t stream)
{
    const float* k       = (const float*)d_in[0];
    const float* q       = (const float*)d_in[1];
    const float* W_score = (const float*)d_in[2];
    const float* W_enh   = (const float*)d_in[3];
    const float* b_enh   = (const float*)d_in[4];
    const float* W_mask  = (const float*)d_in[5];
    const float* b_mask  = (const float*)d_in[6];
    float* out = (float*)d_out;

    char* ws = (char*)d_ws;
    const size_t MH = (size_t)B_ * T_ * H_;   // 4.096M elems
    float* qs  = (float*)ws;                  // [M,256] f32; later reused as enh
    float* c   = (float*)(ws + MH * 4);       // [M,256] f32
    char* wsp  = ws + 2 * MH * 4;
    unsigned short* wsh = (unsigned short*)(wsp);
    unsigned short* wsl = wsh + 65536;
    unsigned short* weh = wsl + 65536;
    unsigned short* wel = weh + 131072;
    unsigned short* wmh = wel + 131072;
    unsigned short* wml = wmh + 81920;        // 320x256 padded
    float* enh = qs;                          // alias: qs dead after band_attn

    dim3 blk(256);

    // 0) split all weights into bf16 hi/lo (W_mask zero-padded to 320 rows)
    split_weights<<<dim3(1088), blk, 0, stream>>>(
        W_score, W_enh, W_mask, wsh, wsl, weh, wel, wmh, wml);

    // 1) qs = q @ W_score^T
    gemm_mfma<0, false><<<dim3(125, 4), blk, 0, stream>>>(
        q, nullptr, wsh, wsl, nullptr, qs, 8, 256, 256, 256);

    // 2) banded attention -> c
    band_attn<<<dim3(B_ * T_ / TQ), blk, 0, stream>>>(qs, k, c);

    // 3) enh = tanh([c,q] @ W_enh^T + b_enh)
    gemm_mfma<1, true><<<dim3(125, 4), blk, 0, stream>>>(
        c, q, weh, wel, b_enh, enh, 16, 512, 256, 256);

    // 4) out = sigmoid(enh @ W_mask^T + b_mask)
    gemm_mfma<2, false><<<dim3(125, 5), blk, 0, stream>>>(
        enh, nullptr, wmh, wml, b_mask, out, 8, 256, 257, 257);
}

// Round 5
// 143.796 us; speedup vs baseline: 2.2368x; 1.1979x over previous
//
#include <hip/hip_runtime.h>
#include <math.h>

#define B_    8
#define T_    2000
#define H_    256
#define FOUT_ 257
#define ALEN_ 128

typedef __attribute__((ext_vector_type(8))) short bf16x8;
typedef __attribute__((ext_vector_type(4))) float f32x4;
typedef __attribute__((ext_vector_type(16))) float f32x16;
typedef __attribute__((ext_vector_type(8))) unsigned short u16x8;

// ---------------------------------------------------------------------------
__device__ __forceinline__ unsigned short f2bf(float x) {   // RNE
    unsigned u = __builtin_bit_cast(unsigned, x);
    return (unsigned short)((u + 0x7FFFu + ((u >> 16) & 1u)) >> 16);
}
__device__ __forceinline__ float bf2f(unsigned short h) {
    unsigned u = ((unsigned)h) << 16;
    return __builtin_bit_cast(float, u);
}
// truncation split: x = hi + lo exactly at f32; hi top-16, lo = x - hi
__device__ __forceinline__ void split1(float x, unsigned short& h, unsigned short& l) {
    unsigned u = __builtin_bit_cast(unsigned, x);
    h = (unsigned short)(u >> 16);
    float hf = __builtin_bit_cast(float, u & 0xFFFF0000u);
    l = (unsigned short)(__builtin_bit_cast(unsigned, x - hf) >> 16);
}
__device__ __forceinline__ void split8(float4 f0, float4 f1, bf16x8& h, bf16x8& l) {
    float f[8] = {f0.x, f0.y, f0.z, f0.w, f1.x, f1.y, f1.z, f1.w};
#pragma unroll
    for (int i = 0; i < 8; ++i) {
        unsigned short hh, ll;
        split1(f[i], hh, ll);
        h[i] = (short)hh; l[i] = (short)ll;
    }
}
__device__ __forceinline__ void gld16(const void* g, void* l) {
    __builtin_amdgcn_global_load_lds(
        (const __attribute__((address_space(1))) unsigned*)g,
        (__attribute__((address_space(3))) unsigned*)l, 16, 0, 0);
}

// ---------------------------------------------------------------------------
// Split f32 weights into bf16 hi/lo (RNE hi). Blocks [0,256) W_score,
// [256,768) W_enh, [768,1088) W_mask padded to 320x256 rows (zeros >= 257).
__global__ __launch_bounds__(256) void split_weights(
    const float* __restrict__ Ws, const float* __restrict__ We,
    const float* __restrict__ Wm,
    unsigned short* __restrict__ wsh, unsigned short* __restrict__ wsl,
    unsigned short* __restrict__ weh, unsigned short* __restrict__ wel,
    unsigned short* __restrict__ wmh, unsigned short* __restrict__ wml)
{
    const int bx = blockIdx.x, tid = threadIdx.x;
    if (bx < 256) {
        const int idx = bx * 256 + tid;
        const float x = Ws[idx];
        const unsigned short h = f2bf(x);
        wsh[idx] = h; wsl[idx] = f2bf(x - bf2f(h));
    } else if (bx < 768) {
        const int idx = (bx - 256) * 256 + tid;
        const float x = We[idx];
        const unsigned short h = f2bf(x);
        weh[idx] = h; wel[idx] = f2bf(x - bf2f(h));
    } else {
        const int idx = (bx - 768) * 256 + tid;
        const int r = idx >> 8;
        const float x = (r < FOUT_) ? Wm[idx] : 0.f;
        const unsigned short h = f2bf(x);
        wmh[idx] = h; wml[idx] = f2bf(x - bf2f(h));
    }
}

// ---------------------------------------------------------------------------
// kprep: transpose k into bf16-hi K^T [8][256][2016] (s-padded; pad left
// uninitialized — multiplied only by P=0, and 0xAA bf16 is a normal number).
__global__ __launch_bounds__(256) void kprep(
    const float* __restrict__ kin, unsigned short* __restrict__ kth)
{
    __shared__ float tile[16][260];
    const int bid = blockIdx.x;
    const int b = bid / 125;
    const int s0 = (bid % 125) * 16;
    const int tid = threadIdx.x;
    const int r = tid >> 4, cs = (tid & 15) * 16;

    const float* src = kin + ((size_t)b * T_ + s0 + r) * H_ + cs;
#pragma unroll
    for (int i = 0; i < 4; ++i) {
        const float4 v = *(const float4*)(src + i * 4);
        tile[r][cs + i * 4 + 0] = v.x;
        tile[r][cs + i * 4 + 1] = v.y;
        tile[r][cs + i * 4 + 2] = v.z;
        tile[r][cs + i * 4 + 3] = v.w;
    }
    __syncthreads();

    const int h = tid;
    u16x8 o0, o1;
#pragma unroll
    for (int s = 0; s < 8; ++s)
        o0[s] = (unsigned short)(__builtin_bit_cast(unsigned, tile[s][h]) >> 16);
#pragma unroll
    for (int s = 0; s < 8; ++s)
        o1[s] = (unsigned short)(__builtin_bit_cast(unsigned, tile[s + 8][h]) >> 16);
    unsigned short* dst = kth + ((size_t)b * H_ + h) * 2016 + s0;
    *(u16x8*)(dst) = o0;
    *(u16x8*)(dst + 8) = o1;
}

// ---------------------------------------------------------------------------
// Split-bf16 MFMA GEMM (R4-proven). SPLITOUT=true writes hi/lo bf16 arrays
// instead of f32 C (used for qs, consumed by band_attn_mfma).
template <int ACT, bool HAS_A2, bool SPLITOUT>
__global__ __launch_bounds__(256) void gemm_mfma(
    const float* __restrict__ A1, const float* __restrict__ A2,
    const unsigned short* __restrict__ Wh, const unsigned short* __restrict__ Wl,
    const float* __restrict__ bias, float* __restrict__ C,
    unsigned short* __restrict__ Ch, unsigned short* __restrict__ Cl,
    int NT, int KB, int NSTORE, int LDC)
{
    __shared__ unsigned short AH[2][128 * 32];
    __shared__ unsigned short AL[2][128 * 32];
    __shared__ unsigned short BH[2][64 * 32];
    __shared__ unsigned short BL[2][64 * 32];

    const int tid = threadIdx.x;
    const int m0 = blockIdx.x * 128;
    const int n0 = blockIdx.y * 64;
    const int w = tid >> 6, l = tid & 63;
    const int wr = w >> 1, wc = w & 1;
    const int lm = l & 31, hh = l >> 5;

    f32x16 acc0 = {};
    f32x16 acc1 = {};
    float4 areg[4];

    auto LOADA = [&](int kt) {
        const int k0 = kt * 32;
        const float* base = A1;
        int kk = k0;
        if (HAS_A2 && k0 >= 256) { base = A2; kk = k0 - 256; }
#pragma unroll
        for (int p = 0; p < 4; ++p) {
            const int row = p * 32 + (tid >> 3);
            areg[p] = *(const float4*)(base + (size_t)(m0 + row) * 256 + kk + (tid & 7) * 4);
        }
    };
    auto WRITEA = [&](int buf) {
#pragma unroll
        for (int p = 0; p < 4; ++p) {
            const int row = p * 32 + (tid >> 3);
            const unsigned off = row * 64 + ((((tid & 7) * 8)) ^ ((row & 3) << 4));
            const float x0 = areg[p].x, x1 = areg[p].y, x2 = areg[p].z, x3 = areg[p].w;
            const unsigned short h0 = f2bf(x0), h1 = f2bf(x1), h2 = f2bf(x2), h3 = f2bf(x3);
            short4 hv = make_short4((short)h0, (short)h1, (short)h2, (short)h3);
            short4 lv = make_short4((short)f2bf(x0 - bf2f(h0)), (short)f2bf(x1 - bf2f(h1)),
                                    (short)f2bf(x2 - bf2f(h2)), (short)f2bf(x3 - bf2f(h3)));
            *(short4*)((char*)AH[buf] + off) = hv;
            *(short4*)((char*)AL[buf] + off) = lv;
        }
    };
    auto STAGEW = [&](int kt, int buf) {
        const int k0 = kt * 32;
        const int row = tid >> 2, slot = tid & 3;
        const size_t so = (size_t)(n0 + row) * KB + k0 + (size_t)((slot ^ (row & 3)) * 8);
        char* dh = (char*)BH[buf] + (tid >> 6) * 1024;
        char* dl = (char*)BL[buf] + (tid >> 6) * 1024;
        gld16(Wh + so, dh);
        gld16(Wl + so, dl);
    };

    LOADA(0);
    STAGEW(0, 0);
    WRITEA(0);
    __syncthreads();

    int buf = 0;
    for (int kt = 0; kt < NT; ++kt) {
        const bool last = (kt == NT - 1);
        if (!last) { LOADA(kt + 1); STAGEW(kt + 1, buf ^ 1); }

#pragma unroll
        for (int kc = 0; kc < 2; ++kc) {
            const unsigned kslot = (unsigned)((kc * 2 + hh) * 16);
            const unsigned bo = (unsigned)((wc * 32 + lm) * 64) + (kslot ^ ((lm & 3) << 4));
            const bf16x8 bh = *(const bf16x8*)((const char*)BH[buf] + bo);
            const bf16x8 bl = *(const bf16x8*)((const char*)BL[buf] + bo);
            const unsigned r0 = (unsigned)(wr * 64 + lm);
            const unsigned ao0 = r0 * 64 + (kslot ^ ((r0 & 3) << 4));
            const unsigned ao1 = ao0 + 32 * 64;
            const bf16x8 ah0 = *(const bf16x8*)((const char*)AH[buf] + ao0);
            const bf16x8 al0 = *(const bf16x8*)((const char*)AL[buf] + ao0);
            const bf16x8 ah1 = *(const bf16x8*)((const char*)AH[buf] + ao1);
            const bf16x8 al1 = *(const bf16x8*)((const char*)AL[buf] + ao1);
            acc0 = __builtin_amdgcn_mfma_f32_32x32x16_bf16(ah0, bh, acc0, 0, 0, 0);
            acc0 = __builtin_amdgcn_mfma_f32_32x32x16_bf16(ah0, bl, acc0, 0, 0, 0);
            acc0 = __builtin_amdgcn_mfma_f32_32x32x16_bf16(al0, bh, acc0, 0, 0, 0);
            acc1 = __builtin_amdgcn_mfma_f32_32x32x16_bf16(ah1, bh, acc1, 0, 0, 0);
            acc1 = __builtin_amdgcn_mfma_f32_32x32x16_bf16(ah1, bl, acc1, 0, 0, 0);
            acc1 = __builtin_amdgcn_mfma_f32_32x32x16_bf16(al1, bh, acc1, 0, 0, 0);
        }

        if (!last) WRITEA(buf ^ 1);
        __syncthreads();
        buf ^= 1;
    }

    const int gcol = n0 + wc * 32 + lm;
    if (gcol < NSTORE) {
        const float bv = bias ? bias[gcol] : 0.f;
#pragma unroll
        for (int rt = 0; rt < 2; ++rt) {
            const f32x16 r = rt ? acc1 : acc0;
#pragma unroll
            for (int e = 0; e < 16; ++e) {
                const int rowl = (e & 3) + 8 * (e >> 2) + 4 * hh;
                const int gr = m0 + wr * 64 + rt * 32 + rowl;
                float x = r[e] + bv;
                if constexpr (ACT == 1) x = tanhf(x);
                else if constexpr (ACT == 2) x = 1.f / (1.f + expf(-x));
                if constexpr (SPLITOUT) {
                    unsigned short hh2, ll2;
                    split1(x, hh2, ll2);
                    Ch[(size_t)gr * LDC + gcol] = hh2;
                    Cl[(size_t)gr * LDC + gcol] = ll2;
                } else {
                    C[(size_t)gr * LDC + gcol] = x;
                }
            }
        }
    }
}

// ---------------------------------------------------------------------------
// MFMA banded attention. Block = 256 thr (4 waves) handles 16 queries of one
// batch. Band-only max (exact substitution, as before).
//
// QK^T (3-term split): D[q][s] via mfma_f32_16x16x32_bf16, A = qs (pre-split
//   hi/lo, 16B frag loads), B = K^T frags = contiguous row-major k reads +
//   in-register trunc split. Wave w owns s-tiles {w, w+4, w+8} (9 tiles, 144 s).
// Softmax in LDS: thread (q = tid>>4, 16 lanes per q), band-masked, P scaled
//   by 1/denom, split into PH/PL bf16 (zero outside band, all 160 written).
// PV (2-term: (PH+PL)*KT_hi): A = P from LDS (16B frags), B = pre-transposed
//   bf16 K^T (kprep) 16B contiguous frags. Wave w owns h-tiles {w,w+4,w+8,w+12}.
// Frag layouts (R4-proven family): A row=l%16 k=(l/16)*8+e; B col=l%16 same k;
// D col=l&15, row=(l>>4)*4+reg (m89-verified).
__global__ __launch_bounds__(256) void band_attn_mfma(
    const unsigned short* __restrict__ qh, const unsigned short* __restrict__ ql,
    const float* __restrict__ kin, const unsigned short* __restrict__ kth,
    float* __restrict__ cout)
{
    __shared__ float S[16][164];
    __shared__ unsigned short PH[16][168];
    __shared__ unsigned short PL[16][168];

    const int bid = blockIdx.x;
    const int b = bid / 125;
    const int t0 = (bid % 125) * 16;
    const int tid = threadIdx.x;
    const int w = tid >> 6, l = tid & 63;
    const int lq = l & 15;      // frag row/col index
    const int lk = l >> 4;      // k-group 0..3
    const int s_lo = max(0, t0 - ALEN_);
    const size_t qrow = (size_t)b * T_ + t0;
    const size_t kb = (size_t)b * T_ * H_;

    // ---- QK^T ----
    bf16x8 aH[8], aL[8];
#pragma unroll
    for (int hc = 0; hc < 8; ++hc) {
        const size_t o = (qrow + lq) * H_ + hc * 32 + lk * 8;
        aH[hc] = *(const bf16x8*)(qh + o);
        aL[hc] = *(const bf16x8*)(ql + o);
    }
    for (int st = w; st < 9; st += 4) {
        f32x4 acc = {};
        const int s = s_lo + st * 16 + lq;  // B col (always < 2000)
#pragma unroll
        for (int hc = 0; hc < 8; ++hc) {
            const float* kp = kin + kb + (size_t)s * H_ + hc * 32 + lk * 8;
            const float4 f0 = *(const float4*)(kp);
            const float4 f1 = *(const float4*)(kp + 4);
            bf16x8 bh, bl;
            split8(f0, f1, bh, bl);
            acc = __builtin_amdgcn_mfma_f32_16x16x32_bf16(aH[hc], bh, acc, 0, 0, 0);
            acc = __builtin_amdgcn_mfma_f32_16x16x32_bf16(aH[hc], bl, acc, 0, 0, 0);
            acc = __builtin_amdgcn_mfma_f32_16x16x32_bf16(aL[hc], bh, acc, 0, 0, 0);
        }
#pragma unroll
        for (int r = 0; r < 4; ++r)
            S[lk * 4 + r][st * 16 + lq] = acc[r];
    }
    __syncthreads();

    // ---- softmax (band-masked, P pre-scaled by 1/denom) ----
    {
        const int q = tid >> 4, li = tid & 15;
        const int t = t0 + q;
        const int jlo = max(0, t - ALEN_) - s_lo;
        const int jhi = t - s_lo;            // <= 143
        float m = -INFINITY;
#pragma unroll
        for (int j = 0; j < 10; ++j) {
            const int s = li + j * 16;
            if (s >= jlo && s <= jhi) m = fmaxf(m, S[q][s]);
        }
#pragma unroll
        for (int off = 8; off; off >>= 1) m = fmaxf(m, __shfl_xor(m, off));
        float sum = 0.f;
#pragma unroll
        for (int j = 0; j < 10; ++j) {
            const int s = li + j * 16;
            const float e = (s >= jlo && s <= jhi) ? expf(S[q][s] - m) : 0.f;
            S[q][s] = e;
            sum += e;
        }
#pragma unroll
        for (int off = 8; off; off >>= 1) sum += __shfl_xor(sum, off);
        const float inv = 1.f / (sum + 1e-30f);
#pragma unroll
        for (int j = 0; j < 10; ++j) {
            const int s = li + j * 16;
            unsigned short hh2, ll2;
            split1(S[q][s] * inv, hh2, ll2);
            PH[q][s] = hh2;
            PL[q][s] = ll2;
        }
    }
    __syncthreads();

    // ---- PV ----
    for (int ht = w; ht < 16; ht += 4) {
        const int h = ht * 16 + lq;          // B col
        f32x4 acc = {};
        const unsigned short* ktp = kth + ((size_t)b * H_ + h) * 2016 + s_lo;
#pragma unroll
        for (int sc = 0; sc < 5; ++sc) {
            const bf16x8 ph = *(const bf16x8*)((const char*)&PH[lq][0] + sc * 64 + lk * 16);
            const bf16x8 pl = *(const bf16x8*)((const char*)&PL[lq][0] + sc * 64 + lk * 16);
            const bf16x8 bt = *(const bf16x8*)(ktp + sc * 32 + lk * 8);
            acc = __builtin_amdgcn_mfma_f32_16x16x32_bf16(ph, bt, acc, 0, 0, 0);
            acc = __builtin_amdgcn_mfma_f32_16x16x32_bf16(pl, bt, acc, 0, 0, 0);
        }
#pragma unroll
        for (int r = 0; r < 4; ++r)
            cout[(qrow + lk * 4 + r) * H_ + ht * 16 + lq] = acc[r];
    }
}

// ---------------------------------------------------------------------------
extern "C" void kernel_launch(void* const* d_in, const int* in_sizes, int n_in,
                              void* d_out, int out_size, void* d_ws, size_t ws_size,
                              hipStream_t stream)
{
    const float* k       = (const float*)d_in[0];
    const float* q       = (const float*)d_in[1];
    const float* W_score = (const float*)d_in[2];
    const float* W_enh   = (const float*)d_in[3];
    const float* b_enh   = (const float*)d_in[4];
    const float* W_mask  = (const float*)d_in[5];
    const float* b_mask  = (const float*)d_in[6];
    float* out = (float*)d_out;

    char* ws = (char*)d_ws;
    const size_t MH = (size_t)B_ * T_ * H_;         // 4.096M
    unsigned short* qh = (unsigned short*)ws;        // 8.192 MB
    unsigned short* ql = qh + MH;                    // 8.192 MB
    float* c   = (float*)(ws + MH * 4);              // 16.384 MB
    unsigned short* kth = (unsigned short*)(ws + MH * 8);  // 8x256x2016x2B
    char* wsp = ws + MH * 8 + (size_t)B_ * H_ * 2016 * 2;
    unsigned short* wsh = (unsigned short*)(wsp);
    unsigned short* wsl = wsh + 65536;
    unsigned short* weh = wsl + 65536;
    unsigned short* wel = weh + 131072;
    unsigned short* wmh = wel + 131072;
    unsigned short* wml = wmh + 81920;
    float* enh = (float*)ws;                         // aliases qh/ql (dead)

    dim3 blk(256);

    split_weights<<<dim3(1088), blk, 0, stream>>>(
        W_score, W_enh, W_mask, wsh, wsl, weh, wel, wmh, wml);

    kprep<<<dim3(1000), blk, 0, stream>>>(k, kth);

    // qs (split bf16) = q @ W_score^T
    gemm_mfma<0, false, true><<<dim3(125, 4), blk, 0, stream>>>(
        q, nullptr, wsh, wsl, nullptr, nullptr, qh, ql, 8, 256, 256, 256);

    band_attn_mfma<<<dim3(1000), blk, 0, stream>>>(qh, ql, k, kth, c);

    // enh = tanh([c,q] @ W_enh^T + b_enh)
    gemm_mfma<1, true, false><<<dim3(125, 4), blk, 0, stream>>>(
        c, q, weh, wel, b_enh, enh, nullptr, nullptr, 16, 512, 256, 256);

    // out = sigmoid(enh @ W_mask^T + b_mask)
    gemm_mfma<2, false, false><<<dim3(125, 5), blk, 0, stream>>>(
        enh, nullptr, wmh, wml, b_mask, out, nullptr, nullptr, 8, 256, 257, 257);
}

// Round 6
// 138.432 us; speedup vs baseline: 2.3235x; 1.0387x over previous
//
#include <hip/hip_runtime.h>
#include <math.h>

#define B_    8
#define T_    2000
#define H_    256
#define FOUT_ 257
#define ALEN_ 128

typedef __attribute__((ext_vector_type(8))) short bf16x8;
typedef __attribute__((ext_vector_type(4))) float f32x4;
typedef __attribute__((ext_vector_type(16))) float f32x16;
typedef __attribute__((ext_vector_type(8))) unsigned short u16x8;

// ---------------------------------------------------------------------------
__device__ __forceinline__ unsigned short f2bf(float x) {   // RNE
    unsigned u = __builtin_bit_cast(unsigned, x);
    return (unsigned short)((u + 0x7FFFu + ((u >> 16) & 1u)) >> 16);
}
__device__ __forceinline__ float bf2f(unsigned short h) {
    unsigned u = ((unsigned)h) << 16;
    return __builtin_bit_cast(float, u);
}
// truncation split: x = hi + lo exactly at f32
__device__ __forceinline__ void split1(float x, unsigned short& h, unsigned short& l) {
    unsigned u = __builtin_bit_cast(unsigned, x);
    h = (unsigned short)(u >> 16);
    float hf = __builtin_bit_cast(float, u & 0xFFFF0000u);
    l = (unsigned short)(__builtin_bit_cast(unsigned, x - hf) >> 16);
}
__device__ __forceinline__ void split8(float4 f0, float4 f1, bf16x8& h, bf16x8& l) {
    float f[8] = {f0.x, f0.y, f0.z, f0.w, f1.x, f1.y, f1.z, f1.w};
#pragma unroll
    for (int i = 0; i < 8; ++i) {
        unsigned short hh, ll;
        split1(f[i], hh, ll);
        h[i] = (short)hh; l[i] = (short)ll;
    }
}
__device__ __forceinline__ void gld16(const void* g, void* l) {
    __builtin_amdgcn_global_load_lds(
        (const __attribute__((address_space(1))) unsigned*)g,
        (__attribute__((address_space(3))) unsigned*)l, 16, 0, 0);
}

// ---------------------------------------------------------------------------
__global__ __launch_bounds__(256) void split_weights(
    const float* __restrict__ Ws, const float* __restrict__ We,
    const float* __restrict__ Wm,
    unsigned short* __restrict__ wsh, unsigned short* __restrict__ wsl,
    unsigned short* __restrict__ weh, unsigned short* __restrict__ wel,
    unsigned short* __restrict__ wmh, unsigned short* __restrict__ wml)
{
    const int bx = blockIdx.x, tid = threadIdx.x;
    if (bx < 256) {
        const int idx = bx * 256 + tid;
        unsigned short h, l; split1(Ws[idx], h, l);
        wsh[idx] = h; wsl[idx] = l;
    } else if (bx < 768) {
        const int idx = (bx - 256) * 256 + tid;
        unsigned short h, l; split1(We[idx], h, l);
        weh[idx] = h; wel[idx] = l;
    } else {
        const int idx = (bx - 768) * 256 + tid;
        const int r = idx >> 8;
        const float x = (r < FOUT_) ? Wm[idx] : 0.f;
        unsigned short h, l; split1(x, h, l);
        wmh[idx] = h; wml[idx] = l;
    }
}

// ---------------------------------------------------------------------------
// qsplit: q f32 [MH] -> bf16 hi/lo arrays (trunc split), 8 elems/thread.
__global__ __launch_bounds__(256) void qsplit(
    const float* __restrict__ q, unsigned short* __restrict__ qh,
    unsigned short* __restrict__ ql)
{
    const size_t i = ((size_t)blockIdx.x * 256 + threadIdx.x) * 8;
    const float4 f0 = *(const float4*)(q + i);
    const float4 f1 = *(const float4*)(q + i + 4);
    bf16x8 h, l;
    split8(f0, f1, h, l);
    *(bf16x8*)(qh + i) = h;
    *(bf16x8*)(ql + i) = l;
}

// ---------------------------------------------------------------------------
// kprep: transpose k into bf16-hi K^T [8][256][2016] (s-padded).
__global__ __launch_bounds__(256) void kprep(
    const float* __restrict__ kin, unsigned short* __restrict__ kth)
{
    __shared__ float tile[16][260];
    const int bid = blockIdx.x;
    const int b = bid / 125;
    const int s0 = (bid % 125) * 16;
    const int tid = threadIdx.x;
    const int r = tid >> 4, cs = (tid & 15) * 16;

    const float* src = kin + ((size_t)b * T_ + s0 + r) * H_ + cs;
#pragma unroll
    for (int i = 0; i < 4; ++i) {
        const float4 v = *(const float4*)(src + i * 4);
        tile[r][cs + i * 4 + 0] = v.x;
        tile[r][cs + i * 4 + 1] = v.y;
        tile[r][cs + i * 4 + 2] = v.z;
        tile[r][cs + i * 4 + 3] = v.w;
    }
    __syncthreads();

    const int h = tid;
    u16x8 o0, o1;
#pragma unroll
    for (int s = 0; s < 8; ++s)
        o0[s] = (unsigned short)(__builtin_bit_cast(unsigned, tile[s][h]) >> 16);
#pragma unroll
    for (int s = 0; s < 8; ++s)
        o1[s] = (unsigned short)(__builtin_bit_cast(unsigned, tile[s + 8][h]) >> 16);
    unsigned short* dst = kth + ((size_t)b * H_ + h) * 2016 + s0;
    *(u16x8*)(dst) = o0;
    *(u16x8*)(dst + 8) = o1;
}

// ---------------------------------------------------------------------------
// Split-bf16 MFMA GEMM v2: all operands PRE-SPLIT bf16 hi/lo in global.
// C[M,N] = act( A @ W^T + bias ), A = [A1 | A2] along K when HAS_A2.
// Block 256 thr (4 waves), tile 128x64, BK=32, wave tile 64x32 via
// mfma_f32_32x32x16_bf16, 3-term (Ah*Wh + Ah*Wl + Al*Wh).
// LDS rows are 128B [hi 64B | lo 64B], swizzle byte ^= (row&7)<<4 applied on
// BOTH the gld16 per-lane SOURCE address (inverse-permuted) and the frag
// reads (rule #21) -> conflict-free ds_read_b128 at the 8-slot floor.
// All staging is global_load_lds: no reg round-trip, no ds_writes, no VALU.
template <int ACT, bool HAS_A2, bool SPLITOUT>
__global__ __launch_bounds__(256) void gemm_mfma(
    const unsigned short* __restrict__ Ah1, const unsigned short* __restrict__ Al1,
    const unsigned short* __restrict__ Ah2, const unsigned short* __restrict__ Al2,
    const unsigned short* __restrict__ Wh, const unsigned short* __restrict__ Wl,
    const float* __restrict__ bias, float* __restrict__ C,
    unsigned short* __restrict__ Ch, unsigned short* __restrict__ Cl,
    int NT, int KB, int NSTORE, int LDC)
{
    __shared__ char AS[2][128 * 128];   // 2 x 16 KB
    __shared__ char WS[2][64 * 128];    // 2 x 8 KB

    const int tid = threadIdx.x;
    const int m0 = blockIdx.x * 128;
    const int n0 = blockIdx.y * 64;
    const int w = tid >> 6, l = tid & 63;
    const int wr = w >> 1, wc = w & 1;
    const int lm = l & 31, hh = l >> 5;

    f32x16 acc0 = {};
    f32x16 acc1 = {};

    auto STAGEA = [&](int kt, int buf) {
        const int k0g = kt * 32;
        const unsigned short* Hs = Ah1;
        const unsigned short* Ls = Al1;
        int k0 = k0g;
        if (HAS_A2 && k0g >= 256) { Hs = Ah2; Ls = Al2; k0 = k0g - 256; }
#pragma unroll
        for (int p = 0; p < 4; ++p) {
            const unsigned D = p * 4096u + tid * 16u;
            const unsigned row = D >> 7;
            const unsigned u = (D & 127u) ^ ((row & 7u) << 4);
            const unsigned kelem = (u & 63u) >> 1;
            const unsigned short* src =
                ((u >> 6) ? Ls : Hs) + (size_t)(m0 + row) * 256 + k0 + kelem;
            gld16(src, AS[buf] + (p * 4 + w) * 1024);
        }
    };
    auto STAGEW = [&](int kt, int buf) {
        const int k0g = kt * 32;
#pragma unroll
        for (int p = 0; p < 2; ++p) {
            const unsigned D = p * 4096u + tid * 16u;
            const unsigned row = D >> 7;
            const unsigned u = (D & 127u) ^ ((row & 7u) << 4);
            const unsigned kelem = (u & 63u) >> 1;
            const unsigned short* src =
                ((u >> 6) ? Wl : Wh) + (size_t)(n0 + row) * KB + k0g + kelem;
            gld16(src, WS[buf] + (p * 4 + w) * 1024);
        }
    };

    STAGEA(0, 0);
    STAGEW(0, 0);
    __syncthreads();

    int buf = 0;
    for (int kt = 0; kt < NT; ++kt) {
        const bool last = (kt == NT - 1);
        if (!last) { STAGEA(kt + 1, buf ^ 1); STAGEW(kt + 1, buf ^ 1); }

        const unsigned r_b = (unsigned)(wc * 32 + lm);
        const unsigned swb = (r_b & 7u) << 4;
        const unsigned r_a0 = (unsigned)(wr * 64 + lm);
        const unsigned swa = (r_a0 & 7u) << 4;   // (r_a0+32)&7 == r_a0&7
#pragma unroll
        for (int kc = 0; kc < 2; ++kc) {
            const unsigned u = (unsigned)(kc * 32 + hh * 16);
            const bf16x8 bh = *(const bf16x8*)(WS[buf] + r_b * 128 + (u ^ swb));
            const bf16x8 bl = *(const bf16x8*)(WS[buf] + r_b * 128 + ((u + 64) ^ swb));
            const bf16x8 ah0 = *(const bf16x8*)(AS[buf] + r_a0 * 128 + (u ^ swa));
            const bf16x8 al0 = *(const bf16x8*)(AS[buf] + r_a0 * 128 + ((u + 64) ^ swa));
            const bf16x8 ah1 = *(const bf16x8*)(AS[buf] + (r_a0 + 32) * 128 + (u ^ swa));
            const bf16x8 al1 = *(const bf16x8*)(AS[buf] + (r_a0 + 32) * 128 + ((u + 64) ^ swa));
            acc0 = __builtin_amdgcn_mfma_f32_32x32x16_bf16(ah0, bh, acc0, 0, 0, 0);
            acc0 = __builtin_amdgcn_mfma_f32_32x32x16_bf16(ah0, bl, acc0, 0, 0, 0);
            acc0 = __builtin_amdgcn_mfma_f32_32x32x16_bf16(al0, bh, acc0, 0, 0, 0);
            acc1 = __builtin_amdgcn_mfma_f32_32x32x16_bf16(ah1, bh, acc1, 0, 0, 0);
            acc1 = __builtin_amdgcn_mfma_f32_32x32x16_bf16(ah1, bl, acc1, 0, 0, 0);
            acc1 = __builtin_amdgcn_mfma_f32_32x32x16_bf16(al1, bh, acc1, 0, 0, 0);
        }
        __syncthreads();
        buf ^= 1;
    }

    // epilogue: C/D layout col=lane&31, row=(reg&3)+8*(reg>>2)+4*(lane>>5)
    const int gcol = n0 + wc * 32 + lm;
    if (gcol < NSTORE) {
        const float bv = bias ? bias[gcol] : 0.f;
#pragma unroll
        for (int rt = 0; rt < 2; ++rt) {
            const f32x16 r = rt ? acc1 : acc0;
#pragma unroll
            for (int e = 0; e < 16; ++e) {
                const int rowl = (e & 3) + 8 * (e >> 2) + 4 * hh;
                const int gr = m0 + wr * 64 + rt * 32 + rowl;
                float x = r[e] + bv;
                if constexpr (ACT == 1) x = tanhf(x);
                else if constexpr (ACT == 2) x = 1.f / (1.f + expf(-x));
                if constexpr (SPLITOUT) {
                    unsigned short hh2, ll2;
                    split1(x, hh2, ll2);
                    Ch[(size_t)gr * LDC + gcol] = hh2;
                    Cl[(size_t)gr * LDC + gcol] = ll2;
                } else {
                    C[(size_t)gr * LDC + gcol] = x;
                }
            }
        }
    }
}

// ---------------------------------------------------------------------------
// MFMA banded attention (R5-proven), now with SPLIT c output for gemm2.
__global__ __launch_bounds__(256) void band_attn_mfma(
    const unsigned short* __restrict__ qh, const unsigned short* __restrict__ ql,
    const float* __restrict__ kin, const unsigned short* __restrict__ kth,
    unsigned short* __restrict__ Ch, unsigned short* __restrict__ Cl)
{
    __shared__ float S[16][164];
    __shared__ unsigned short PH[16][168];
    __shared__ unsigned short PL[16][168];

    const int bid = blockIdx.x;
    const int b = bid / 125;
    const int t0 = (bid % 125) * 16;
    const int tid = threadIdx.x;
    const int w = tid >> 6, l = tid & 63;
    const int lq = l & 15;
    const int lk = l >> 4;
    const int s_lo = max(0, t0 - ALEN_);
    const size_t qrow = (size_t)b * T_ + t0;
    const size_t kb = (size_t)b * T_ * H_;

    // ---- QK^T ----
    bf16x8 aH[8], aL[8];
#pragma unroll
    for (int hc = 0; hc < 8; ++hc) {
        const size_t o = (qrow + lq) * H_ + hc * 32 + lk * 8;
        aH[hc] = *(const bf16x8*)(qh + o);
        aL[hc] = *(const bf16x8*)(ql + o);
    }
    for (int st = w; st < 9; st += 4) {
        f32x4 acc = {};
        const int s = s_lo + st * 16 + lq;
#pragma unroll
        for (int hc = 0; hc < 8; ++hc) {
            const float* kp = kin + kb + (size_t)s * H_ + hc * 32 + lk * 8;
            const float4 f0 = *(const float4*)(kp);
            const float4 f1 = *(const float4*)(kp + 4);
            bf16x8 bh, bl;
            split8(f0, f1, bh, bl);
            acc = __builtin_amdgcn_mfma_f32_16x16x32_bf16(aH[hc], bh, acc, 0, 0, 0);
            acc = __builtin_amdgcn_mfma_f32_16x16x32_bf16(aH[hc], bl, acc, 0, 0, 0);
            acc = __builtin_amdgcn_mfma_f32_16x16x32_bf16(aL[hc], bh, acc, 0, 0, 0);
        }
#pragma unroll
        for (int r = 0; r < 4; ++r)
            S[lk * 4 + r][st * 16 + lq] = acc[r];
    }
    __syncthreads();

    // ---- softmax (band-masked, P pre-scaled by 1/denom) ----
    {
        const int q = tid >> 4, li = tid & 15;
        const int t = t0 + q;
        const int jlo = max(0, t - ALEN_) - s_lo;
        const int jhi = t - s_lo;
        float m = -INFINITY;
#pragma unroll
        for (int j = 0; j < 10; ++j) {
            const int s = li + j * 16;
            if (s >= jlo && s <= jhi) m = fmaxf(m, S[q][s]);
        }
#pragma unroll
        for (int off = 8; off; off >>= 1) m = fmaxf(m, __shfl_xor(m, off));
        float sum = 0.f;
#pragma unroll
        for (int j = 0; j < 10; ++j) {
            const int s = li + j * 16;
            const float e = (s >= jlo && s <= jhi) ? expf(S[q][s] - m) : 0.f;
            S[q][s] = e;
            sum += e;
        }
#pragma unroll
        for (int off = 8; off; off >>= 1) sum += __shfl_xor(sum, off);
        const float inv = 1.f / (sum + 1e-30f);
#pragma unroll
        for (int j = 0; j < 10; ++j) {
            const int s = li + j * 16;
            unsigned short hh2, ll2;
            split1(S[q][s] * inv, hh2, ll2);
            PH[q][s] = hh2;
            PL[q][s] = ll2;
        }
    }
    __syncthreads();

    // ---- PV ----
    for (int ht = w; ht < 16; ht += 4) {
        const int h = ht * 16 + lq;
        f32x4 acc = {};
        const unsigned short* ktp = kth + ((size_t)b * H_ + h) * 2016 + s_lo;
#pragma unroll
        for (int sc = 0; sc < 5; ++sc) {
            const bf16x8 ph = *(const bf16x8*)((const char*)&PH[lq][0] + sc * 64 + lk * 16);
            const bf16x8 pl = *(const bf16x8*)((const char*)&PL[lq][0] + sc * 64 + lk * 16);
            const bf16x8 bt = *(const bf16x8*)(ktp + sc * 32 + lk * 8);
            acc = __builtin_amdgcn_mfma_f32_16x16x32_bf16(ph, bt, acc, 0, 0, 0);
            acc = __builtin_amdgcn_mfma_f32_16x16x32_bf16(pl, bt, acc, 0, 0, 0);
        }
#pragma unroll
        for (int r = 0; r < 4; ++r) {
            unsigned short hh2, ll2;
            split1(acc[r], hh2, ll2);
            const size_t o = (qrow + lk * 4 + r) * H_ + ht * 16 + lq;
            Ch[o] = hh2;
            Cl[o] = ll2;
        }
    }
}

// ---------------------------------------------------------------------------
extern "C" void kernel_launch(void* const* d_in, const int* in_sizes, int n_in,
                              void* d_out, int out_size, void* d_ws, size_t ws_size,
                              hipStream_t stream)
{
    const float* k       = (const float*)d_in[0];
    const float* q       = (const float*)d_in[1];
    const float* W_score = (const float*)d_in[2];
    const float* W_enh   = (const float*)d_in[3];
    const float* b_enh   = (const float*)d_in[4];
    const float* W_mask  = (const float*)d_in[5];
    const float* b_mask  = (const float*)d_in[6];
    float* out = (float*)d_out;

    const size_t MH = (size_t)B_ * T_ * H_;          // 4.096M elems
    unsigned short* q2h = (unsigned short*)d_ws;     // 8.19 MB each
    unsigned short* q2l = q2h + MH;
    unsigned short* qh  = q2l + MH;
    unsigned short* ql  = qh + MH;
    unsigned short* ch  = ql + MH;
    unsigned short* cl  = ch + MH;
    unsigned short* kth = cl + MH;                   // 8x256x2016
    unsigned short* wsh = kth + (size_t)B_ * H_ * 2016;
    unsigned short* wsl = wsh + 65536;
    unsigned short* weh = wsl + 65536;
    unsigned short* wel = weh + 131072;
    unsigned short* wmh = wel + 131072;
    unsigned short* wml = wmh + 81920;
    unsigned short* eh = qh;                         // alias: qs dead after attn
    unsigned short* el = ql;

    dim3 blk(256);

    split_weights<<<dim3(1088), blk, 0, stream>>>(
        W_score, W_enh, W_mask, wsh, wsl, weh, wel, wmh, wml);

    qsplit<<<dim3(2000), blk, 0, stream>>>(q, q2h, q2l);

    kprep<<<dim3(1000), blk, 0, stream>>>(k, kth);

    // qs (split bf16) = q @ W_score^T
    gemm_mfma<0, false, true><<<dim3(125, 4), blk, 0, stream>>>(
        q2h, q2l, nullptr, nullptr, wsh, wsl, nullptr, nullptr, qh, ql,
        8, 256, 256, 256);

    band_attn_mfma<<<dim3(1000), blk, 0, stream>>>(qh, ql, k, kth, ch, cl);

    // enh (split bf16) = tanh([c,q] @ W_enh^T + b_enh)
    gemm_mfma<1, true, true><<<dim3(125, 4), blk, 0, stream>>>(
        ch, cl, q2h, q2l, weh, wel, b_enh, nullptr, eh, el,
        16, 512, 256, 256);

    // out = sigmoid(enh @ W_mask^T + b_mask)
    gemm_mfma<2, false, false><<<dim3(125, 5), blk, 0, stream>>>(
        eh, el, nullptr, nullptr, wmh, wml, b_mask, out, nullptr, nullptr,
        8, 256, 257, 257);
}

// Round 7
// 131.969 us; speedup vs baseline: 2.4373x; 1.0490x over previous
//
#include <hip/hip_runtime.h>
#include <math.h>

#define B_    8
#define T_    2000
#define H_    256
#define FOUT_ 257
#define ALEN_ 128

typedef __attribute__((ext_vector_type(8))) short bf16x8;
typedef __attribute__((ext_vector_type(4))) float f32x4;
typedef __attribute__((ext_vector_type(16))) float f32x16;
typedef __attribute__((ext_vector_type(8))) unsigned short u16x8;

// ---------------------------------------------------------------------------
// truncation split: x = hi + lo exactly at f32
__device__ __forceinline__ void split1(float x, unsigned short& h, unsigned short& l) {
    unsigned u = __builtin_bit_cast(unsigned, x);
    h = (unsigned short)(u >> 16);
    float hf = __builtin_bit_cast(float, u & 0xFFFF0000u);
    l = (unsigned short)(__builtin_bit_cast(unsigned, x - hf) >> 16);
}
__device__ __forceinline__ void split8(float4 f0, float4 f1, bf16x8& h, bf16x8& l) {
    float f[8] = {f0.x, f0.y, f0.z, f0.w, f1.x, f1.y, f1.z, f1.w};
#pragma unroll
    for (int i = 0; i < 8; ++i) {
        unsigned short hh, ll;
        split1(f[i], hh, ll);
        h[i] = (short)hh; l[i] = (short)ll;
    }
}
__device__ __forceinline__ void gld16(const void* g, void* l) {
    __builtin_amdgcn_global_load_lds(
        (const __attribute__((address_space(1))) unsigned*)g,
        (__attribute__((address_space(3))) unsigned*)l, 16, 0, 0);
}

// ---------------------------------------------------------------------------
// prep: one kernel for all preprocessing.
//  blocks [0,2000):    qsplit  q -> q2h/q2l
//  blocks [2000,3000): kprep   k -> kth (bf16-hi K^T, [8][256][2016])
//  blocks [3000,3256): W_score split
//  blocks [3256,3768): W_enh split
//  blocks [3768,4280): W_mask split, padded to 512x256 (zero rows >= 257)
__global__ __launch_bounds__(256) void prep(
    const float* __restrict__ k, const float* __restrict__ q,
    const float* __restrict__ Ws, const float* __restrict__ We,
    const float* __restrict__ Wm,
    unsigned short* __restrict__ q2h, unsigned short* __restrict__ q2l,
    unsigned short* __restrict__ kth,
    unsigned short* __restrict__ wsh, unsigned short* __restrict__ wsl,
    unsigned short* __restrict__ weh, unsigned short* __restrict__ wel,
    unsigned short* __restrict__ wmh, unsigned short* __restrict__ wml)
{
    __shared__ float tile[16][260];
    const int bx = blockIdx.x, tid = threadIdx.x;

    if (bx < 2000) {                     // ---- qsplit (8 elems/thread)
        const size_t i = ((size_t)bx * 256 + tid) * 8;
        const float4 f0 = *(const float4*)(q + i);
        const float4 f1 = *(const float4*)(q + i + 4);
        bf16x8 h, l;
        split8(f0, f1, h, l);
        *(bf16x8*)(q2h + i) = h;
        *(bf16x8*)(q2l + i) = l;
    } else if (bx < 3000) {              // ---- kprep (transpose to bf16-hi)
        const int bid = bx - 2000;
        const int b = bid / 125;
        const int s0 = (bid % 125) * 16;
        const int r = tid >> 4, cs = (tid & 15) * 16;
        const float* src = k + ((size_t)b * T_ + s0 + r) * H_ + cs;
#pragma unroll
        for (int i = 0; i < 4; ++i) {
            const float4 v = *(const float4*)(src + i * 4);
            tile[r][cs + i * 4 + 0] = v.x;
            tile[r][cs + i * 4 + 1] = v.y;
            tile[r][cs + i * 4 + 2] = v.z;
            tile[r][cs + i * 4 + 3] = v.w;
        }
        __syncthreads();
        const int h = tid;
        u16x8 o0, o1;
#pragma unroll
        for (int s = 0; s < 8; ++s)
            o0[s] = (unsigned short)(__builtin_bit_cast(unsigned, tile[s][h]) >> 16);
#pragma unroll
        for (int s = 0; s < 8; ++s)
            o1[s] = (unsigned short)(__builtin_bit_cast(unsigned, tile[s + 8][h]) >> 16);
        unsigned short* dst = kth + ((size_t)b * H_ + h) * 2016 + s0;
        *(u16x8*)(dst) = o0;
        *(u16x8*)(dst + 8) = o1;
    } else if (bx < 3256) {              // ---- W_score
        const int idx = (bx - 3000) * 256 + tid;
        unsigned short h, l; split1(Ws[idx], h, l);
        wsh[idx] = h; wsl[idx] = l;
    } else if (bx < 3768) {              // ---- W_enh
        const int idx = (bx - 3256) * 256 + tid;
        unsigned short h, l; split1(We[idx], h, l);
        weh[idx] = h; wel[idx] = l;
    } else {                             // ---- W_mask (padded to 512 rows)
        const int idx = (bx - 3768) * 256 + tid;
        const int r = idx >> 8;
        const float x = (r < FOUT_) ? Wm[idx] : 0.f;
        unsigned short h, l; split1(x, h, l);
        wmh[idx] = h; wml[idx] = l;
    }
}

// ---------------------------------------------------------------------------
// Split-bf16 MFMA GEMM v3: BM=64, BN=256 (full N -> A staged exactly once).
// C[M,N] = act( A @ W^T + bias ), A = [A1 | A2] along K when HAS_A2, all
// operands pre-split bf16 hi/lo. Block 256 thr (4 waves); wave w owns the
// 64x64 output tile at cols n0 + w*64. mfma_f32_32x32x16_bf16, 3-term.
// LDS rows 128B [hi 64B | lo 64B], swizzle byte ^= (row&7)<<4 on both the
// gld16 source (inverse-permuted) and the frag reads (rule #21).
template <int ACT, bool HAS_A2, bool SPLITOUT>
__global__ __launch_bounds__(256) void gemm_mfma(
    const unsigned short* __restrict__ Ah1, const unsigned short* __restrict__ Al1,
    const unsigned short* __restrict__ Ah2, const unsigned short* __restrict__ Al2,
    const unsigned short* __restrict__ Wh, const unsigned short* __restrict__ Wl,
    const float* __restrict__ bias, float* __restrict__ C,
    unsigned short* __restrict__ Ch, unsigned short* __restrict__ Cl,
    int NT, int KB, int NSTORE, int LDC)
{
    __shared__ char AS[2][64 * 128];     // 2 x 8 KB
    __shared__ char WS[2][256 * 128];    // 2 x 32 KB

    const int tid = threadIdx.x;
    const int m0 = blockIdx.x * 64;
    const int n0 = blockIdx.y * 256;
    const int w = tid >> 6, l = tid & 63;
    const int lm = l & 31, hh = l >> 5;

    f32x16 acc00 = {}, acc01 = {}, acc10 = {}, acc11 = {};

    auto STAGEA = [&](int kt, int buf) {
        const int k0g = kt * 32;
        const unsigned short* Hs = Ah1;
        const unsigned short* Ls = Al1;
        int k0 = k0g;
        if (HAS_A2 && k0g >= 256) { Hs = Ah2; Ls = Al2; k0 = k0g - 256; }
#pragma unroll
        for (int p = 0; p < 2; ++p) {
            const unsigned D = p * 4096u + tid * 16u;
            const unsigned row = D >> 7;
            const unsigned u = (D & 127u) ^ ((row & 7u) << 4);
            const unsigned kelem = (u & 63u) >> 1;
            const unsigned short* src =
                ((u >> 6) ? Ls : Hs) + (size_t)(m0 + row) * 256 + k0 + kelem;
            gld16(src, AS[buf] + (p * 4 + w) * 1024);
        }
    };
    auto STAGEW = [&](int kt, int buf) {
        const int k0g = kt * 32;
#pragma unroll
        for (int p = 0; p < 8; ++p) {
            const unsigned D = p * 4096u + tid * 16u;
            const unsigned row = D >> 7;
            const unsigned u = (D & 127u) ^ ((row & 7u) << 4);
            const unsigned kelem = (u & 63u) >> 1;
            const unsigned short* src =
                ((u >> 6) ? Wl : Wh) + (size_t)(n0 + row) * KB + k0g + kelem;
            gld16(src, WS[buf] + (p * 4 + w) * 1024);
        }
    };

    STAGEA(0, 0);
    STAGEW(0, 0);
    __syncthreads();

    int buf = 0;
    for (int kt = 0; kt < NT; ++kt) {
        const bool last = (kt == NT - 1);
        if (!last) { STAGEA(kt + 1, buf ^ 1); STAGEW(kt + 1, buf ^ 1); }

        const unsigned r_a = (unsigned)lm;             // rows lm, lm+32
        const unsigned swa = (r_a & 7u) << 4;
        const unsigned r_b = (unsigned)(w * 64 + lm);  // cols, +32
        const unsigned swb = (r_b & 7u) << 4;
#pragma unroll
        for (int kc = 0; kc < 2; ++kc) {
            const unsigned u = (unsigned)(kc * 32 + hh * 16);
            const bf16x8 ah0 = *(const bf16x8*)(AS[buf] + r_a * 128 + (u ^ swa));
            const bf16x8 al0 = *(const bf16x8*)(AS[buf] + r_a * 128 + ((u + 64) ^ swa));
            const bf16x8 ah1 = *(const bf16x8*)(AS[buf] + (r_a + 32) * 128 + (u ^ swa));
            const bf16x8 al1 = *(const bf16x8*)(AS[buf] + (r_a + 32) * 128 + ((u + 64) ^ swa));
            const bf16x8 bh0 = *(const bf16x8*)(WS[buf] + r_b * 128 + (u ^ swb));
            const bf16x8 bl0 = *(const bf16x8*)(WS[buf] + r_b * 128 + ((u + 64) ^ swb));
            const bf16x8 bh1 = *(const bf16x8*)(WS[buf] + (r_b + 32) * 128 + (u ^ swb));
            const bf16x8 bl1 = *(const bf16x8*)(WS[buf] + (r_b + 32) * 128 + ((u + 64) ^ swb));
            acc00 = __builtin_amdgcn_mfma_f32_32x32x16_bf16(ah0, bh0, acc00, 0, 0, 0);
            acc00 = __builtin_amdgcn_mfma_f32_32x32x16_bf16(ah0, bl0, acc00, 0, 0, 0);
            acc00 = __builtin_amdgcn_mfma_f32_32x32x16_bf16(al0, bh0, acc00, 0, 0, 0);
            acc01 = __builtin_amdgcn_mfma_f32_32x32x16_bf16(ah0, bh1, acc01, 0, 0, 0);
            acc01 = __builtin_amdgcn_mfma_f32_32x32x16_bf16(ah0, bl1, acc01, 0, 0, 0);
            acc01 = __builtin_amdgcn_mfma_f32_32x32x16_bf16(al0, bh1, acc01, 0, 0, 0);
            acc10 = __builtin_amdgcn_mfma_f32_32x32x16_bf16(ah1, bh0, acc10, 0, 0, 0);
            acc10 = __builtin_amdgcn_mfma_f32_32x32x16_bf16(ah1, bl0, acc10, 0, 0, 0);
            acc10 = __builtin_amdgcn_mfma_f32_32x32x16_bf16(al1, bh0, acc10, 0, 0, 0);
            acc11 = __builtin_amdgcn_mfma_f32_32x32x16_bf16(ah1, bh1, acc11, 0, 0, 0);
            acc11 = __builtin_amdgcn_mfma_f32_32x32x16_bf16(ah1, bl1, acc11, 0, 0, 0);
            acc11 = __builtin_amdgcn_mfma_f32_32x32x16_bf16(al1, bh1, acc11, 0, 0, 0);
        }
        __syncthreads();
        buf ^= 1;
    }

    // epilogue: C/D layout col=lane&31, row=(reg&3)+8*(reg>>2)+4*(lane>>5)
#pragma unroll
    for (int rt = 0; rt < 2; ++rt) {
#pragma unroll
        for (int ct = 0; ct < 2; ++ct) {
            const f32x16 r = rt ? (ct ? acc11 : acc10) : (ct ? acc01 : acc00);
            const int gcol = n0 + w * 64 + ct * 32 + lm;
            if (gcol < NSTORE) {
                const float bv = bias ? bias[gcol] : 0.f;
#pragma unroll
                for (int e = 0; e < 16; ++e) {
                    const int rowl = (e & 3) + 8 * (e >> 2) + 4 * hh;
                    const int gr = m0 + rt * 32 + rowl;
                    float x = r[e] + bv;
                    if constexpr (ACT == 1) x = tanhf(x);
                    else if constexpr (ACT == 2) x = 1.f / (1.f + expf(-x));
                    if constexpr (SPLITOUT) {
                        unsigned short hh2, ll2;
                        split1(x, hh2, ll2);
                        Ch[(size_t)gr * LDC + gcol] = hh2;
                        Cl[(size_t)gr * LDC + gcol] = ll2;
                    } else {
                        C[(size_t)gr * LDC + gcol] = x;
                    }
                }
            }
        }
    }
}

// ---------------------------------------------------------------------------
// MFMA banded attention (R5/R6-proven), split c output.
__global__ __launch_bounds__(256) void band_attn_mfma(
    const unsigned short* __restrict__ qh, const unsigned short* __restrict__ ql,
    const float* __restrict__ kin, const unsigned short* __restrict__ kth,
    unsigned short* __restrict__ Ch, unsigned short* __restrict__ Cl)
{
    __shared__ float S[16][164];
    __shared__ unsigned short PH[16][168];
    __shared__ unsigned short PL[16][168];

    const int bid = blockIdx.x;
    const int b = bid / 125;
    const int t0 = (bid % 125) * 16;
    const int tid = threadIdx.x;
    const int w = tid >> 6, l = tid & 63;
    const int lq = l & 15;
    const int lk = l >> 4;
    const int s_lo = max(0, t0 - ALEN_);
    const size_t qrow = (size_t)b * T_ + t0;
    const size_t kb = (size_t)b * T_ * H_;

    // ---- QK^T ----
    bf16x8 aH[8], aL[8];
#pragma unroll
    for (int hc = 0; hc < 8; ++hc) {
        const size_t o = (qrow + lq) * H_ + hc * 32 + lk * 8;
        aH[hc] = *(const bf16x8*)(qh + o);
        aL[hc] = *(const bf16x8*)(ql + o);
    }
    for (int st = w; st < 9; st += 4) {
        f32x4 acc = {};
        const int s = s_lo + st * 16 + lq;
#pragma unroll
        for (int hc = 0; hc < 8; ++hc) {
            const float* kp = kin + kb + (size_t)s * H_ + hc * 32 + lk * 8;
            const float4 f0 = *(const float4*)(kp);
            const float4 f1 = *(const float4*)(kp + 4);
            bf16x8 bh, bl;
            split8(f0, f1, bh, bl);
            acc = __builtin_amdgcn_mfma_f32_16x16x32_bf16(aH[hc], bh, acc, 0, 0, 0);
            acc = __builtin_amdgcn_mfma_f32_16x16x32_bf16(aH[hc], bl, acc, 0, 0, 0);
            acc = __builtin_amdgcn_mfma_f32_16x16x32_bf16(aL[hc], bh, acc, 0, 0, 0);
        }
#pragma unroll
        for (int r = 0; r < 4; ++r)
            S[lk * 4 + r][st * 16 + lq] = acc[r];
    }
    __syncthreads();

    // ---- softmax (band-masked, P pre-scaled by 1/denom) ----
    {
        const int q = tid >> 4, li = tid & 15;
        const int t = t0 + q;
        const int jlo = max(0, t - ALEN_) - s_lo;
        const int jhi = t - s_lo;
        float m = -INFINITY;
#pragma unroll
        for (int j = 0; j < 10; ++j) {
            const int s = li + j * 16;
            if (s >= jlo && s <= jhi) m = fmaxf(m, S[q][s]);
        }
#pragma unroll
        for (int off = 8; off; off >>= 1) m = fmaxf(m, __shfl_xor(m, off));
        float sum = 0.f;
#pragma unroll
        for (int j = 0; j < 10; ++j) {
            const int s = li + j * 16;
            const float e = (s >= jlo && s <= jhi) ? expf(S[q][s] - m) : 0.f;
            S[q][s] = e;
            sum += e;
        }
#pragma unroll
        for (int off = 8; off; off >>= 1) sum += __shfl_xor(sum, off);
        const float inv = 1.f / (sum + 1e-30f);
#pragma unroll
        for (int j = 0; j < 10; ++j) {
            const int s = li + j * 16;
            unsigned short hh2, ll2;
            split1(S[q][s] * inv, hh2, ll2);
            PH[q][s] = hh2;
            PL[q][s] = ll2;
        }
    }
    __syncthreads();

    // ---- PV ----
    for (int ht = w; ht < 16; ht += 4) {
        const int h = ht * 16 + lq;
        f32x4 acc = {};
        const unsigned short* ktp = kth + ((size_t)b * H_ + h) * 2016 + s_lo;
#pragma unroll
        for (int sc = 0; sc < 5; ++sc) {
            const bf16x8 ph = *(const bf16x8*)((const char*)&PH[lq][0] + sc * 64 + lk * 16);
            const bf16x8 pl = *(const bf16x8*)((const char*)&PL[lq][0] + sc * 64 + lk * 16);
            const bf16x8 bt = *(const bf16x8*)(ktp + sc * 32 + lk * 8);
            acc = __builtin_amdgcn_mfma_f32_16x16x32_bf16(ph, bt, acc, 0, 0, 0);
            acc = __builtin_amdgcn_mfma_f32_16x16x32_bf16(pl, bt, acc, 0, 0, 0);
        }
#pragma unroll
        for (int r = 0; r < 4; ++r) {
            unsigned short hh2, ll2;
            split1(acc[r], hh2, ll2);
            const size_t o = (qrow + lk * 4 + r) * H_ + ht * 16 + lq;
            Ch[o] = hh2;
            Cl[o] = ll2;
        }
    }
}

// ---------------------------------------------------------------------------
extern "C" void kernel_launch(void* const* d_in, const int* in_sizes, int n_in,
                              void* d_out, int out_size, void* d_ws, size_t ws_size,
                              hipStream_t stream)
{
    const float* k       = (const float*)d_in[0];
    const float* q       = (const float*)d_in[1];
    const float* W_score = (const float*)d_in[2];
    const float* W_enh   = (const float*)d_in[3];
    const float* b_enh   = (const float*)d_in[4];
    const float* W_mask  = (const float*)d_in[5];
    const float* b_mask  = (const float*)d_in[6];
    float* out = (float*)d_out;

    const size_t MH = (size_t)B_ * T_ * H_;          // 4.096M elems
    unsigned short* q2h = (unsigned short*)d_ws;     // 8.19 MB each
    unsigned short* q2l = q2h + MH;
    unsigned short* qh  = q2l + MH;
    unsigned short* ql  = qh + MH;
    unsigned short* ch  = ql + MH;
    unsigned short* cl  = ch + MH;
    unsigned short* kth = cl + MH;                   // 8x256x2016
    unsigned short* wsh = kth + (size_t)B_ * H_ * 2016;
    unsigned short* wsl = wsh + 65536;
    unsigned short* weh = wsl + 65536;
    unsigned short* wel = weh + 131072;
    unsigned short* wmh = wel + 131072;              // 512x256 padded
    unsigned short* wml = wmh + 131072;
    unsigned short* eh = qh;                         // alias: qs dead after attn
    unsigned short* el = ql;

    dim3 blk(256);

    prep<<<dim3(4280), blk, 0, stream>>>(
        k, q, W_score, W_enh, W_mask,
        q2h, q2l, kth, wsh, wsl, weh, wel, wmh, wml);

    // qs (split bf16) = q @ W_score^T
    gemm_mfma<0, false, true><<<dim3(250, 1), blk, 0, stream>>>(
        q2h, q2l, nullptr, nullptr, wsh, wsl, nullptr, nullptr, qh, ql,
        8, 256, 256, 256);

    band_attn_mfma<<<dim3(1000), blk, 0, stream>>>(qh, ql, k, kth, ch, cl);

    // enh (split bf16) = tanh([c,q] @ W_enh^T + b_enh)
    gemm_mfma<1, true, true><<<dim3(250, 1), blk, 0, stream>>>(
        ch, cl, q2h, q2l, weh, wel, b_enh, nullptr, eh, el,
        16, 512, 256, 256);

    // out = sigmoid(enh @ W_mask^T + b_mask)
    gemm_mfma<2, false, false><<<dim3(250, 2), blk, 0, stream>>>(
        eh, el, nullptr, nullptr, wmh, wml, b_mask, out, nullptr, nullptr,
        8, 256, 257, 257);
}

// Round 8
// 122.838 us; speedup vs baseline: 2.6185x; 1.0743x over previous
//
#include <hip/hip_runtime.h>
#include <math.h>

#define B_    8
#define T_    2000
#define H_    256
#define FOUT_ 257
#define ALEN_ 128

typedef __attribute__((ext_vector_type(8))) short bf16x8;
typedef __attribute__((ext_vector_type(4))) float f32x4;
typedef __attribute__((ext_vector_type(16))) float f32x16;
typedef __attribute__((ext_vector_type(8))) unsigned short u16x8;

// ---------------------------------------------------------------------------
// truncation split: x = hi + lo exactly at f32
__device__ __forceinline__ void split1(float x, unsigned short& h, unsigned short& l) {
    unsigned u = __builtin_bit_cast(unsigned, x);
    h = (unsigned short)(u >> 16);
    float hf = __builtin_bit_cast(float, u & 0xFFFF0000u);
    l = (unsigned short)(__builtin_bit_cast(unsigned, x - hf) >> 16);
}
__device__ __forceinline__ void split8(float4 f0, float4 f1, bf16x8& h, bf16x8& l) {
    float f[8] = {f0.x, f0.y, f0.z, f0.w, f1.x, f1.y, f1.z, f1.w};
#pragma unroll
    for (int i = 0; i < 8; ++i) {
        unsigned short hh, ll;
        split1(f[i], hh, ll);
        h[i] = (short)hh; l[i] = (short)ll;
    }
}
__device__ __forceinline__ void gld16(const void* g, void* l) {
    __builtin_amdgcn_global_load_lds(
        (const __attribute__((address_space(1))) unsigned*)g,
        (__attribute__((address_space(3))) unsigned*)l, 16, 0, 0);
}

// ---------------------------------------------------------------------------
// prep: one kernel for all preprocessing.
//  blocks [0,2000):    qsplit  q -> q2h/q2l
//  blocks [2000,3008): kprep   k -> ktn, PV-frag-ordered bf16-hi K^T:
//                      ktn[b][ht(16)][g(126)][half(2)][lq(16)][e(8)]
//                      element (b, h=ht*16+lq, s=g*16+half*8+e).
//                      g=125 tile (s>=2000) zero-filled.
//  blocks [3008,3264): W_score split
//  blocks [3264,3776): W_enh split
//  blocks [3776,4288): W_mask split, padded to 512x256 (zero rows >= 257)
__global__ __launch_bounds__(256) void prep(
    const float* __restrict__ k, const float* __restrict__ q,
    const float* __restrict__ Ws, const float* __restrict__ We,
    const float* __restrict__ Wm,
    unsigned short* __restrict__ q2h, unsigned short* __restrict__ q2l,
    unsigned short* __restrict__ ktn,
    unsigned short* __restrict__ wsh, unsigned short* __restrict__ wsl,
    unsigned short* __restrict__ weh, unsigned short* __restrict__ wel,
    unsigned short* __restrict__ wmh, unsigned short* __restrict__ wml)
{
    __shared__ float tile[16][260];
    const int bx = blockIdx.x, tid = threadIdx.x;

    if (bx < 2000) {                     // ---- qsplit (8 elems/thread)
        const size_t i = ((size_t)bx * 256 + tid) * 8;
        const float4 f0 = *(const float4*)(q + i);
        const float4 f1 = *(const float4*)(q + i + 4);
        bf16x8 h, l;
        split8(f0, f1, h, l);
        *(bf16x8*)(q2h + i) = h;
        *(bf16x8*)(q2l + i) = l;
    } else if (bx < 3008) {              // ---- kprep (frag-ordered bf16-hi K^T)
        const int bid = bx - 2000;
        const int b = bid / 126;
        const int g = bid % 126;
        const int s0 = g * 16;
        const int r = tid >> 4, cs = (tid & 15) * 16;
        const int s = s0 + r;
        if (s < T_) {
            const float* src = k + ((size_t)b * T_ + s) * H_ + cs;
#pragma unroll
            for (int i = 0; i < 4; ++i) {
                const float4 v = *(const float4*)(src + i * 4);
                tile[r][cs + i * 4 + 0] = v.x;
                tile[r][cs + i * 4 + 1] = v.y;
                tile[r][cs + i * 4 + 2] = v.z;
                tile[r][cs + i * 4 + 3] = v.w;
            }
        } else {
#pragma unroll
            for (int i = 0; i < 16; ++i) tile[r][cs + i] = 0.f;
        }
        __syncthreads();
        const int h = tid;               // column of the 16x256 tile
        const int ht = h >> 4, lq = h & 15;
        u16x8 o0, o1;
#pragma unroll
        for (int ss = 0; ss < 8; ++ss)
            o0[ss] = (unsigned short)(__builtin_bit_cast(unsigned, tile[ss][h]) >> 16);
#pragma unroll
        for (int ss = 0; ss < 8; ++ss)
            o1[ss] = (unsigned short)(__builtin_bit_cast(unsigned, tile[ss + 8][h]) >> 16);
        unsigned short* dst = ktn + (((size_t)(b * 16 + ht) * 126) + g) * 256 + lq * 8;
        *(u16x8*)(dst) = o0;             // half 0: s = g*16 + 0..7
        *(u16x8*)(dst + 128) = o1;       // half 1: s = g*16 + 8..15
    } else if (bx < 3264) {              // ---- W_score
        const int idx = (bx - 3008) * 256 + tid;
        unsigned short h, l; split1(Ws[idx], h, l);
        wsh[idx] = h; wsl[idx] = l;
    } else if (bx < 3776) {              // ---- W_enh
        const int idx = (bx - 3264) * 256 + tid;
        unsigned short h, l; split1(We[idx], h, l);
        weh[idx] = h; wel[idx] = l;
    } else {                             // ---- W_mask (padded to 512 rows)
        const int idx = (bx - 3776) * 256 + tid;
        const int r2 = idx >> 8;
        const float x = (r2 < FOUT_) ? Wm[idx] : 0.f;
        unsigned short h, l; split1(x, h, l);
        wmh[idx] = h; wml[idx] = l;
    }
}

// ---------------------------------------------------------------------------
// Split-bf16 MFMA GEMM v3 (R7-proven): BM=64, BN=256, A staged exactly once.
template <int ACT, bool HAS_A2, bool SPLITOUT>
__global__ __launch_bounds__(256) void gemm_mfma(
    const unsigned short* __restrict__ Ah1, const unsigned short* __restrict__ Al1,
    const unsigned short* __restrict__ Ah2, const unsigned short* __restrict__ Al2,
    const unsigned short* __restrict__ Wh, const unsigned short* __restrict__ Wl,
    const float* __restrict__ bias, float* __restrict__ C,
    unsigned short* __restrict__ Ch, unsigned short* __restrict__ Cl,
    int NT, int KB, int NSTORE, int LDC)
{
    __shared__ char AS[2][64 * 128];     // 2 x 8 KB
    __shared__ char WS[2][256 * 128];    // 2 x 32 KB

    const int tid = threadIdx.x;
    const int m0 = blockIdx.x * 64;
    const int n0 = blockIdx.y * 256;
    const int w = tid >> 6, l = tid & 63;
    const int lm = l & 31, hh = l >> 5;

    f32x16 acc00 = {}, acc01 = {}, acc10 = {}, acc11 = {};

    auto STAGEA = [&](int kt, int buf) {
        const int k0g = kt * 32;
        const unsigned short* Hs = Ah1;
        const unsigned short* Ls = Al1;
        int k0 = k0g;
        if (HAS_A2 && k0g >= 256) { Hs = Ah2; Ls = Al2; k0 = k0g - 256; }
#pragma unroll
        for (int p = 0; p < 2; ++p) {
            const unsigned D = p * 4096u + tid * 16u;
            const unsigned row = D >> 7;
            const unsigned u = (D & 127u) ^ ((row & 7u) << 4);
            const unsigned kelem = (u & 63u) >> 1;
            const unsigned short* src =
                ((u >> 6) ? Ls : Hs) + (size_t)(m0 + row) * 256 + k0 + kelem;
            gld16(src, AS[buf] + (p * 4 + w) * 1024);
        }
    };
    auto STAGEW = [&](int kt, int buf) {
        const int k0g = kt * 32;
#pragma unroll
        for (int p = 0; p < 8; ++p) {
            const unsigned D = p * 4096u + tid * 16u;
            const unsigned row = D >> 7;
            const unsigned u = (D & 127u) ^ ((row & 7u) << 4);
            const unsigned kelem = (u & 63u) >> 1;
            const unsigned short* src =
                ((u >> 6) ? Wl : Wh) + (size_t)(n0 + row) * KB + k0g + kelem;
            gld16(src, WS[buf] + (p * 4 + w) * 1024);
        }
    };

    STAGEA(0, 0);
    STAGEW(0, 0);
    __syncthreads();

    int buf = 0;
    for (int kt = 0; kt < NT; ++kt) {
        const bool last = (kt == NT - 1);
        if (!last) { STAGEA(kt + 1, buf ^ 1); STAGEW(kt + 1, buf ^ 1); }

        const unsigned r_a = (unsigned)lm;
        const unsigned swa = (r_a & 7u) << 4;
        const unsigned r_b = (unsigned)(w * 64 + lm);
        const unsigned swb = (r_b & 7u) << 4;
#pragma unroll
        for (int kc = 0; kc < 2; ++kc) {
            const unsigned u = (unsigned)(kc * 32 + hh * 16);
            const bf16x8 ah0 = *(const bf16x8*)(AS[buf] + r_a * 128 + (u ^ swa));
            const bf16x8 al0 = *(const bf16x8*)(AS[buf] + r_a * 128 + ((u + 64) ^ swa));
            const bf16x8 ah1 = *(const bf16x8*)(AS[buf] + (r_a + 32) * 128 + (u ^ swa));
            const bf16x8 al1 = *(const bf16x8*)(AS[buf] + (r_a + 32) * 128 + ((u + 64) ^ swa));
            const bf16x8 bh0 = *(const bf16x8*)(WS[buf] + r_b * 128 + (u ^ swb));
            const bf16x8 bl0 = *(const bf16x8*)(WS[buf] + r_b * 128 + ((u + 64) ^ swb));
            const bf16x8 bh1 = *(const bf16x8*)(WS[buf] + (r_b + 32) * 128 + (u ^ swb));
            const bf16x8 bl1 = *(const bf16x8*)(WS[buf] + (r_b + 32) * 128 + ((u + 64) ^ swb));
            acc00 = __builtin_amdgcn_mfma_f32_32x32x16_bf16(ah0, bh0, acc00, 0, 0, 0);
            acc00 = __builtin_amdgcn_mfma_f32_32x32x16_bf16(ah0, bl0, acc00, 0, 0, 0);
            acc00 = __builtin_amdgcn_mfma_f32_32x32x16_bf16(al0, bh0, acc00, 0, 0, 0);
            acc01 = __builtin_amdgcn_mfma_f32_32x32x16_bf16(ah0, bh1, acc01, 0, 0, 0);
            acc01 = __builtin_amdgcn_mfma_f32_32x32x16_bf16(ah0, bl1, acc01, 0, 0, 0);
            acc01 = __builtin_amdgcn_mfma_f32_32x32x16_bf16(al0, bh1, acc01, 0, 0, 0);
            acc10 = __builtin_amdgcn_mfma_f32_32x32x16_bf16(ah1, bh0, acc10, 0, 0, 0);
            acc10 = __builtin_amdgcn_mfma_f32_32x32x16_bf16(ah1, bl0, acc10, 0, 0, 0);
            acc10 = __builtin_amdgcn_mfma_f32_32x32x16_bf16(al1, bh0, acc10, 0, 0, 0);
            acc11 = __builtin_amdgcn_mfma_f32_32x32x16_bf16(ah1, bh1, acc11, 0, 0, 0);
            acc11 = __builtin_amdgcn_mfma_f32_32x32x16_bf16(ah1, bl1, acc11, 0, 0, 0);
            acc11 = __builtin_amdgcn_mfma_f32_32x32x16_bf16(al1, bh1, acc11, 0, 0, 0);
        }
        __syncthreads();
        buf ^= 1;
    }

    // epilogue: C/D layout col=lane&31, row=(reg&3)+8*(reg>>2)+4*(lane>>5)
#pragma unroll
    for (int rt = 0; rt < 2; ++rt) {
#pragma unroll
        for (int ct = 0; ct < 2; ++ct) {
            const f32x16 r = rt ? (ct ? acc11 : acc10) : (ct ? acc01 : acc00);
            const int gcol = n0 + w * 64 + ct * 32 + lm;
            if (gcol < NSTORE) {
                const float bv = bias ? bias[gcol] : 0.f;
#pragma unroll
                for (int e = 0; e < 16; ++e) {
                    const int rowl = (e & 3) + 8 * (e >> 2) + 4 * hh;
                    const int gr = m0 + rt * 32 + rowl;
                    float x = r[e] + bv;
                    if constexpr (ACT == 1) x = tanhf(x);
                    else if constexpr (ACT == 2) x = 1.f / (1.f + expf(-x));
                    if constexpr (SPLITOUT) {
                        unsigned short hh2, ll2;
                        split1(x, hh2, ll2);
                        Ch[(size_t)gr * LDC + gcol] = hh2;
                        Cl[(size_t)gr * LDC + gcol] = ll2;
                    } else {
                        C[(size_t)gr * LDC + gcol] = x;
                    }
                }
            }
        }
    }
}

// ---------------------------------------------------------------------------
// MFMA banded attention v4:
//  - XCD-locality swizzle: b = bid&7, tt = bid>>3 -> all 125 t-tiles of one
//    batch land on one XCD (k slice 2MB + ktn 1MB fit its 4MB L2).
//  - PV reads frag-ordered ktn: each (ht,sc) read is 1KB wave-contiguous
//    (was 16 lines/instr at stride 4032B = 4x fetch amplification).
__global__ __launch_bounds__(256) void band_attn_mfma(
    const unsigned short* __restrict__ qh, const unsigned short* __restrict__ ql,
    const float* __restrict__ kin, const unsigned short* __restrict__ ktn,
    unsigned short* __restrict__ Ch, unsigned short* __restrict__ Cl)
{
    __shared__ float S[16][164];
    __shared__ unsigned short PH[16][168];
    __shared__ unsigned short PL[16][168];

    const int bid = blockIdx.x;
    const int b = bid & 7;
    const int t0 = (bid >> 3) * 16;
    const int tid = threadIdx.x;
    const int w = tid >> 6, l = tid & 63;
    const int lq = l & 15;
    const int lk = l >> 4;
    const int s_lo = max(0, t0 - ALEN_);
    const size_t qrow = (size_t)b * T_ + t0;
    const size_t kb = (size_t)b * T_ * H_;

    // ---- QK^T ----
    bf16x8 aH[8], aL[8];
#pragma unroll
    for (int hc = 0; hc < 8; ++hc) {
        const size_t o = (qrow + lq) * H_ + hc * 32 + lk * 8;
        aH[hc] = *(const bf16x8*)(qh + o);
        aL[hc] = *(const bf16x8*)(ql + o);
    }
    for (int st = w; st < 9; st += 4) {
        f32x4 acc = {};
        const int s = s_lo + st * 16 + lq;
#pragma unroll
        for (int hc = 0; hc < 8; ++hc) {
            const float* kp = kin + kb + (size_t)s * H_ + hc * 32 + lk * 8;
            const float4 f0 = *(const float4*)(kp);
            const float4 f1 = *(const float4*)(kp + 4);
            bf16x8 bh, bl;
            split8(f0, f1, bh, bl);
            acc = __builtin_amdgcn_mfma_f32_16x16x32_bf16(aH[hc], bh, acc, 0, 0, 0);
            acc = __builtin_amdgcn_mfma_f32_16x16x32_bf16(aH[hc], bl, acc, 0, 0, 0);
            acc = __builtin_amdgcn_mfma_f32_16x16x32_bf16(aL[hc], bh, acc, 0, 0, 0);
        }
#pragma unroll
        for (int r = 0; r < 4; ++r)
            S[lk * 4 + r][st * 16 + lq] = acc[r];
    }
    __syncthreads();

    // ---- softmax (band-masked, P pre-scaled by 1/denom) ----
    {
        const int q = tid >> 4, li = tid & 15;
        const int t = t0 + q;
        const int jlo = max(0, t - ALEN_) - s_lo;
        const int jhi = t - s_lo;
        float m = -INFINITY;
#pragma unroll
        for (int j = 0; j < 10; ++j) {
            const int s = li + j * 16;
            if (s >= jlo && s <= jhi) m = fmaxf(m, S[q][s]);
        }
#pragma unroll
        for (int off = 8; off; off >>= 1) m = fmaxf(m, __shfl_xor(m, off));
        float sum = 0.f;
#pragma unroll
        for (int j = 0; j < 10; ++j) {
            const int s = li + j * 16;
            const float e = (s >= jlo && s <= jhi) ? expf(S[q][s] - m) : 0.f;
            S[q][s] = e;
            sum += e;
        }
#pragma unroll
        for (int off = 8; off; off >>= 1) sum += __shfl_xor(sum, off);
        const float inv = 1.f / (sum + 1e-30f);
#pragma unroll
        for (int j = 0; j < 10; ++j) {
            const int s = li + j * 16;
            unsigned short hh2, ll2;
            split1(S[q][s] * inv, hh2, ll2);
            PH[q][s] = hh2;
            PL[q][s] = ll2;
        }
    }
    __syncthreads();

    // ---- PV (frag-ordered ktn reads) ----
    const int gbase = s_lo >> 4;
    for (int ht = w; ht < 16; ht += 4) {
        f32x4 acc = {};
        const unsigned short* ktb = ktn + ((size_t)(b * 16 + ht) * 126) * 256;
#pragma unroll
        for (int sc = 0; sc < 5; ++sc) {
            const bf16x8 ph = *(const bf16x8*)((const char*)&PH[lq][0] + sc * 64 + lk * 16);
            const bf16x8 pl = *(const bf16x8*)((const char*)&PL[lq][0] + sc * 64 + lk * 16);
            const bf16x8 bt = *(const bf16x8*)(
                ktb + (size_t)(gbase + 2 * sc + (lk >> 1)) * 256 + (lk & 1) * 128 + lq * 8);
            acc = __builtin_amdgcn_mfma_f32_16x16x32_bf16(ph, bt, acc, 0, 0, 0);
            acc = __builtin_amdgcn_mfma_f32_16x16x32_bf16(pl, bt, acc, 0, 0, 0);
        }
#pragma unroll
        for (int r = 0; r < 4; ++r) {
            unsigned short hh2, ll2;
            split1(acc[r], hh2, ll2);
            const size_t o = (qrow + lk * 4 + r) * H_ + ht * 16 + lq;
            Ch[o] = hh2;
            Cl[o] = ll2;
        }
    }
}

// ---------------------------------------------------------------------------
extern "C" void kernel_launch(void* const* d_in, const int* in_sizes, int n_in,
                              void* d_out, int out_size, void* d_ws, size_t ws_size,
                              hipStream_t stream)
{
    const float* k       = (const float*)d_in[0];
    const float* q       = (const float*)d_in[1];
    const float* W_score = (const float*)d_in[2];
    const float* W_enh   = (const float*)d_in[3];
    const float* b_enh   = (const float*)d_in[4];
    const float* W_mask  = (const float*)d_in[5];
    const float* b_mask  = (const float*)d_in[6];
    float* out = (float*)d_out;

    const size_t MH = (size_t)B_ * T_ * H_;          // 4.096M elems
    unsigned short* q2h = (unsigned short*)d_ws;     // 8.19 MB each
    unsigned short* q2l = q2h + MH;
    unsigned short* qh  = q2l + MH;
    unsigned short* ql  = qh + MH;
    unsigned short* ch  = ql + MH;
    unsigned short* cl  = ch + MH;
    unsigned short* ktn = cl + MH;                   // 8*16*126*256 = 4,128,768
    unsigned short* wsh = ktn + (size_t)B_ * 16 * 126 * 256;
    unsigned short* wsl = wsh + 65536;
    unsigned short* weh = wsl + 65536;
    unsigned short* wel = weh + 131072;
    unsigned short* wmh = wel + 131072;              // 512x256 padded
    unsigned short* wml = wmh + 131072;
    unsigned short* eh = qh;                         // alias: qs dead after attn
    unsigned short* el = ql;

    dim3 blk(256);

    prep<<<dim3(4288), blk, 0, stream>>>(
        k, q, W_score, W_enh, W_mask,
        q2h, q2l, ktn, wsh, wsl, weh, wel, wmh, wml);

    // qs (split bf16) = q @ W_score^T
    gemm_mfma<0, false, true><<<dim3(250, 1), blk, 0, stream>>>(
        q2h, q2l, nullptr, nullptr, wsh, wsl, nullptr, nullptr, qh, ql,
        8, 256, 256, 256);

    band_attn_mfma<<<dim3(1000), blk, 0, stream>>>(qh, ql, k, ktn, ch, cl);

    // enh (split bf16) = tanh([c,q] @ W_enh^T + b_enh)
    gemm_mfma<1, true, true><<<dim3(250, 1), blk, 0, stream>>>(
        ch, cl, q2h, q2l, weh, wel, b_enh, nullptr, eh, el,
        16, 512, 256, 256);

    // out = sigmoid(enh @ W_mask^T + b_mask)
    gemm_mfma<2, false, false><<<dim3(250, 2), blk, 0, stream>>>(
        eh, el, nullptr, nullptr, wmh, wml, b_mask, out, nullptr, nullptr,
        8, 256, 257, 257);
}